// Round 7
// baseline (751.622 us; speedup 1.0000x reference)
//
#include <hip/hip_runtime.h>
#include <hip/hip_fp16.h>
#include <math.h>

#define N_NODES 50000
#define N_EDGES 800000
#define ATOMF 64
#define DIN 192
#define DOUT 128
#define EPB 64
#define NTILES (N_EDGES / EPB)   // 12500
#define LDW 200                  // LDS row stride in bf16 (192 data + 8 pad = 25 x 16B chunks)
#define NSLOT (EPB * 25)         // 1600 16B-chunks per tile

typedef __attribute__((ext_vector_type(8))) short bf16x8;
typedef __attribute__((ext_vector_type(8))) short s16x8;
typedef __attribute__((ext_vector_type(4))) float f32x4;

__device__ __forceinline__ short f2bf(float f) {
  unsigned u = __float_as_uint(f);
  u += 0x7fffu + ((u >> 16) & 1u);   // RNE
  return (short)(u >> 16);
}
__device__ __forceinline__ float bf2f(unsigned short u) {
  return __uint_as_float(((unsigned)u) << 16);
}
__device__ __forceinline__ unsigned short f2h(float f) {
  __half h = __float2half_rn(f);     // v_cvt_f16_f32 (RNE)
  return *(unsigned short*)&h;
}
__device__ __forceinline__ float h2f(unsigned short u) {
  __half h = *(__half*)&u;
  return __half2float(h);            // v_cvt_f32_f16
}
__device__ __forceinline__ float softplus_f(float x) {
  return fmaxf(x, 0.f) + log1pf(__expf(-fabsf(x)));
}
__device__ __forceinline__ float sigmoid_f(float x) {
  return 1.f / (1.f + __expf(-x));
}
// fast variants for the 51.2M-element msg pass (err ~1e-6, threshold 0.24)
__device__ __forceinline__ float fast_sigmoid(float x) {
  return __builtin_amdgcn_rcpf(1.f + __expf(-x));
}
__device__ __forceinline__ float fast_softplus(float x) {
  return fmaxf(x, 0.f) + __logf(1.f + __expf(-fabsf(x)));
}

#define GLOAD16(g, l)                                                          \
  __builtin_amdgcn_global_load_lds(                                            \
      (const __attribute__((address_space(1))) void*)(g),                      \
      (__attribute__((address_space(3))) void*)(l), 16, 0, 0)

// ---------------- fp32 -> bf16 pre-convert (atom table + nbr features) -------
__launch_bounds__(256)
__global__ void precvt_k(const float* __restrict__ atom,
                         const float* __restrict__ nbr,
                         unsigned short* __restrict__ atom_bf,
                         unsigned short* __restrict__ nbr_bf) {
  const int NA = N_NODES * ATOMF / 8;        // 400000 chunks of 8
  const int NB = N_EDGES * ATOMF / 8;        // 6400000
  int stride = gridDim.x * blockDim.x;
  for (int i = blockIdx.x * blockDim.x + threadIdx.x; i < NA + NB; i += stride) {
    const float* s;
    unsigned short* d;
    if (i < NA) { s = atom + (size_t)i * 8; d = atom_bf + (size_t)i * 8; }
    else        { s = nbr + (size_t)(i - NA) * 8; d = nbr_bf + (size_t)(i - NA) * 8; }
    float4 a = ((const float4*)s)[0];
    float4 b = ((const float4*)s)[1];
    s16x8 t;
    t[0] = f2bf(a.x); t[1] = f2bf(a.y); t[2] = f2bf(a.z); t[3] = f2bf(a.w);
    t[4] = f2bf(b.x); t[5] = f2bf(b.y); t[6] = f2bf(b.z); t[7] = f2bf(b.w);
    *(s16x8*)d = t;
  }
}

// ---------------- CSR build: histogram -> scan -> fill (inverse perm) --------
__launch_bounds__(256)
__global__ void hist_k(const int* __restrict__ edst, int* __restrict__ deg) {
  int gid = blockIdx.x * 256 + threadIdx.x;
  if (gid < N_EDGES) atomicAdd(&deg[edst[gid]], 1);
}

__launch_bounds__(1024)
__global__ void scan_k(const int* __restrict__ deg,
                       int* __restrict__ rowptr,
                       int* __restrict__ cursor) {
  __shared__ int wsum[16];
  const int tid = threadIdx.x;
  const int lane = tid & 63, wv = tid >> 6;
  int base = 0;
  for (int c0 = 0; c0 < N_NODES; c0 += 1024) {
    int i = c0 + tid;
    int v = (i < N_NODES) ? deg[i] : 0;
    int s = v;
    #pragma unroll
    for (int d = 1; d < 64; d <<= 1) {
      int t = __shfl_up(s, d, 64);
      if (lane >= d) s += t;
    }
    if (lane == 63) wsum[wv] = s;
    __syncthreads();
    if (wv == 0 && lane < 16) {
      int ws = wsum[lane];
      #pragma unroll
      for (int d = 1; d < 16; d <<= 1) {
        int t = __shfl_up(ws, d, 64);
        if (lane >= d) ws += t;
      }
      wsum[lane] = ws;
    }
    __syncthreads();
    int wbase = wv ? wsum[wv - 1] : 0;
    int excl = base + wbase + s - v;
    if (i < N_NODES) { rowptr[i] = excl; cursor[i] = excl; }
    int tot = wsum[15];
    __syncthreads();   // everyone done reading wsum before next iter overwrites
    base += tot;
  }
  if (tid == 0) rowptr[N_NODES] = base;   // == N_EDGES
}

__launch_bounds__(256)
__global__ void fill_k(const int* __restrict__ edst,
                       int* __restrict__ cursor,
                       int* __restrict__ iperm) {
  int gid = blockIdx.x * 256 + threadIdx.x;
  if (gid < N_EDGES) {
    int pos = atomicAdd(&cursor[edst[gid]], 1);
    iperm[gid] = pos;          // inverse perm: edge -> CSR slot
  }
}

// ---------------- single edge pass: gather -> MFMA -> z store + stats --------
// zt layout: zt[tile][col(128)][row(64)] fp16 (tile-transposed for wide stores)
// Single LDS buffer, invariant: reads only between [A] and [B] barriers,
// stage (overwrite) only after [B]; stage latency hidden under epilogue.
__device__ __forceinline__ void stage_tile(const unsigned short* __restrict__ atom_bf,
                                           const unsigned short* __restrict__ nbr_bf,
                                           const int* __restrict__ esrc,
                                           const int* __restrict__ edst,
                                           int e0, unsigned short* lbase,
                                           const int* g_enc, int wv) {
  #pragma unroll
  for (int it = 0; it < 7; ++it) {
    if (it * 256 + wv * 64 < NSLOT) {        // wave-uniform tail guard
      int e = g_enc[it];
      int row = e & 255;
      int coff = (e >> 8) & 255;
      int sel = e >> 16;
      const unsigned short* src;
      if (sel < 2) {
        const int* ip = sel ? edst : esrc;
        int idx = ip[e0 + row];
        src = atom_bf + (size_t)idx * ATOMF + coff;
      } else {
        src = nbr_bf + (size_t)(e0 + row) * ATOMF + coff;
      }
      GLOAD16(src, lbase + (size_t)(it * 256 + wv * 64) * 8);
    }
  }
}

__launch_bounds__(256, 6)
__global__ void edge_gemm(const unsigned short* __restrict__ atom_bf,
                          const unsigned short* __restrict__ nbr_bf,
                          const int* __restrict__ esrc,
                          const int* __restrict__ edst,
                          const float* __restrict__ W,
                          float* __restrict__ stats,
                          unsigned short* __restrict__ zt) {
  __shared__ unsigned short Tl[EPB * LDW];   // 25600 B, linear (gload_lds dest)

  const int tid = threadIdx.x;
  const int lane = tid & 63;
  const int wv = tid >> 6;
  const int l15 = lane & 15;
  const int lg = lane >> 4;
  const int colF = wv * 16 + l15;            // filter column
  const int colC = colF + 64;                // core column

  // W fragments in registers: wf[cg][kk][jj] = W[kk*32+lg*8+jj][cg*64+colF]
  bf16x8 wf[2][6];
  #pragma unroll
  for (int cg = 0; cg < 2; ++cg) {
    #pragma unroll
    for (int kk = 0; kk < 6; ++kk) {
      bf16x8 t;
      #pragma unroll
      for (int jj = 0; jj < 8; ++jj)
        t[jj] = f2bf(W[(size_t)(kk * 32 + lg * 8 + jj) * 128 + cg * 64 + colF]);
      wf[cg][kk] = t;
    }
  }

  // slot s = it*256+tid -> (row = s/25, w = s%25)
  // w<8: atom[src]; w<16: atom[dst]; w<24: nbr; w==24: pad (harmless load)
  int g_enc[7];
  #pragma unroll
  for (int it = 0; it < 7; ++it) {
    int s = it * 256 + tid;
    if (s >= NSLOT) s = 0;                   // dead slot (wave guard at use)
    int row = s / 25;
    int w = s - row * 25;
    int sel, coff;
    if (w < 8)       { sel = 0; coff = w * 8; }
    else if (w < 16) { sel = 1; coff = (w - 8) * 8; }
    else             { sel = 2; coff = (w < 24 ? (w - 16) * 8 : 0); }
    g_enc[it] = row | (coff << 8) | (sel << 16);
  }

  float fs[2] = {0.f, 0.f}, fq[2] = {0.f, 0.f};

  int t0 = blockIdx.x;
  if (t0 < NTILES)
    stage_tile(atom_bf, nbr_bf, esrc, edst, t0 * EPB, Tl, g_enc, wv);

  for (int tile = t0; tile < NTILES; tile += gridDim.x) {
    __syncthreads();   // [A] vmcnt(0)+lgkmcnt(0) drain: Tl fully staged

    f32x4 acc[2][4] = {};
    #pragma unroll
    for (int rg = 0; rg < 4; ++rg) {
      #pragma unroll
      for (int kk = 0; kk < 6; ++kk) {
        bf16x8 a = *(const bf16x8*)&Tl[(rg * 16 + l15) * LDW + kk * 32 + lg * 8];
        acc[0][rg] = __builtin_amdgcn_mfma_f32_16x16x32_bf16(a, wf[0][kk], acc[0][rg], 0, 0, 0);
        acc[1][rg] = __builtin_amdgcn_mfma_f32_16x16x32_bf16(a, wf[1][kk], acc[1][rg], 0, 0, 0);
      }
    }
    __syncthreads();   // [B] all waves' ds_reads of Tl complete

    int nxt = tile + gridDim.x;
    if (nxt < NTILES)  // stage next tile now; latency hides under epilogue
      stage_tile(atom_bf, nbr_bf, esrc, edst, nxt * EPB, Tl, g_enc, wv);

    // epilogue: stats + fp16 pack + 8B stores; D: row = rg*16 + lg*4 + r
    #pragma unroll
    for (int cg = 0; cg < 2; ++cg) {
      unsigned short* zb = zt + ((size_t)tile * 128 + cg * 64 + colF) * 64 + lg * 4;
      #pragma unroll
      for (int rg = 0; rg < 4; ++rg) {
        float z0 = acc[cg][rg][0], z1 = acc[cg][rg][1];
        float z2 = acc[cg][rg][2], z3 = acc[cg][rg][3];
        fs[cg] += (z0 + z1) + (z2 + z3);
        fq[cg] += z0 * z0 + z1 * z1 + z2 * z2 + z3 * z3;
        uint2 p;
        p.x = (unsigned)f2h(z0) | ((unsigned)f2h(z1) << 16);
        p.y = (unsigned)f2h(z2) | ((unsigned)f2h(z3) << 16);
        *(uint2*)(zb + rg * 16) = p;
      }
    }
    // loop back to [A]: barrier drains the stage's vmcnt before any read
  }

  #pragma unroll
  for (int cg = 0; cg < 2; ++cg) {
    fs[cg] += __shfl_xor(fs[cg], 16, 64); fs[cg] += __shfl_xor(fs[cg], 32, 64);
    fq[cg] += __shfl_xor(fq[cg], 16, 64); fq[cg] += __shfl_xor(fq[cg], 32, 64);
  }
  if (lane < 16) {
    atomicAdd(&stats[colF], fs[0]);
    atomicAdd(&stats[colC], fs[1]);
    atomicAdd(&stats[128 + colF], fq[0]);
    atomicAdd(&stats[128 + colC], fq[1]);
  }
}

// ---------------- BN1 finalize (b_full == 0; bias cancels inside BN anyway) --
__global__ void finalize1_k(const float* __restrict__ stats,
                            const float* __restrict__ g,
                            const float* __restrict__ be,
                            float* __restrict__ ab) {
  int n = threadIdx.x;   // 128
  float mu = stats[n] * (1.f / N_EDGES);
  float var = stats[128 + n] * (1.f / N_EDGES) - mu * mu;
  float a = g[n] * rsqrtf(var + 1e-5f);
  ab[n] = a;
  ab[128 + n] = be[n] - mu * a;
}

// ---------------- gate -> msg in CSR order (via LDS transpose) ---------------
// one block per tile: read zt[tile] (col-major), write msg[iperm[e]][64]
__launch_bounds__(256)
__global__ void msg_k(const unsigned short* __restrict__ zt,
                      const float* __restrict__ ab,
                      const int* __restrict__ iperm,
                      unsigned short* __restrict__ msg) {
  __shared__ unsigned short ml[64][72];      // +8 pad
  const int tile = blockIdx.x;
  const int tid = threadIdx.x;
  const int c = tid & 63;                    // filter col (core = c+64)
  const int rg = tid >> 6;                   // rows rg*16 .. +15
  const unsigned short* fb = zt + ((size_t)tile * 128 + c) * 64 + rg * 16;
  const unsigned short* gb = fb + (size_t)64 * 64;
  s16x8 f0 = *(const s16x8*)fb;
  s16x8 f1 = *(const s16x8*)(fb + 8);
  s16x8 g0 = *(const s16x8*)gb;
  s16x8 g1 = *(const s16x8*)(gb + 8);
  float af = ab[c], cf = ab[128 + c];
  float ag = ab[64 + c], cg = ab[192 + c];
  #pragma unroll
  for (int k = 0; k < 16; ++k) {
    unsigned short fu = (unsigned short)(k < 8 ? f0[k] : f1[k - 8]);
    unsigned short gu = (unsigned short)(k < 8 ? g0[k] : g1[k - 8]);
    float f = af * h2f(fu) + cf;
    float g = ag * h2f(gu) + cg;
    ml[rg * 16 + k][c] = f2h(fast_sigmoid(f) * fast_softplus(g));
  }
  const int r = tid >> 2;
  const int pos = iperm[tile * 64 + r];      // CSR slot for this edge row
  __syncthreads();
  const int cq = (tid & 3) * 16;
  s16x8 o0, o1;
  #pragma unroll
  for (int k = 0; k < 8; ++k) { o0[k] = ml[r][cq + k]; o1[k] = ml[r][cq + 8 + k]; }
  unsigned short* ob = msg + (size_t)pos * 64 + cq;
  *(s16x8*)ob = o0;
  *(s16x8*)(ob + 8) = o1;
}

// ---------------- gather: one wave per node, contiguous CSR rows -------------
__launch_bounds__(256)
__global__ void gather_k(const unsigned short* __restrict__ msg,
                         const int* __restrict__ rowptr,
                         float* __restrict__ out) {
  int n = blockIdx.x * 4 + (threadIdx.x >> 6);
  if (n >= N_NODES) return;
  int lane = threadIdx.x & 63;
  int s = rowptr[n], e = rowptr[n + 1];
  float acc = 0.f;
  for (int i = s; i < e; ++i)
    acc += h2f(msg[(size_t)i * 64 + lane]);
  out[(size_t)n * 64 + lane] = acc;
}

// ---------------- node-side stats / finalize / output ------------------------
__launch_bounds__(256)
__global__ void stats2_k(const float* __restrict__ upd, float* __restrict__ stats2) {
  int tid = threadIdx.x;
  int gid = blockIdx.x * 256 + tid;
  int stride = gridDim.x * 256;
  float4 s = make_float4(0.f, 0.f, 0.f, 0.f);
  float4 q = make_float4(0.f, 0.f, 0.f, 0.f);
  for (int i = gid; i < N_NODES * 16; i += stride) {
    float4 v = ((const float4*)upd)[i];
    s.x += v.x; s.y += v.y; s.z += v.z; s.w += v.w;
    q.x += v.x * v.x; q.y += v.y * v.y; q.z += v.z * v.z; q.w += v.w * v.w;
  }
  int lane = tid & 63;
  int wv = tid >> 6;
  s.x += __shfl_xor(s.x, 16, 64); s.x += __shfl_xor(s.x, 32, 64);
  s.y += __shfl_xor(s.y, 16, 64); s.y += __shfl_xor(s.y, 32, 64);
  s.z += __shfl_xor(s.z, 16, 64); s.z += __shfl_xor(s.z, 32, 64);
  s.w += __shfl_xor(s.w, 16, 64); s.w += __shfl_xor(s.w, 32, 64);
  q.x += __shfl_xor(q.x, 16, 64); q.x += __shfl_xor(q.x, 32, 64);
  q.y += __shfl_xor(q.y, 16, 64); q.y += __shfl_xor(q.y, 32, 64);
  q.z += __shfl_xor(q.z, 16, 64); q.z += __shfl_xor(q.z, 32, 64);
  q.w += __shfl_xor(q.w, 16, 64); q.w += __shfl_xor(q.w, 32, 64);
  __shared__ float red[4 * 128];
  if (lane < 16) {
    int f = lane * 4;
    red[wv * 128 + f + 0] = s.x; red[wv * 128 + f + 1] = s.y;
    red[wv * 128 + f + 2] = s.z; red[wv * 128 + f + 3] = s.w;
    red[wv * 128 + 64 + f + 0] = q.x; red[wv * 128 + 64 + f + 1] = q.y;
    red[wv * 128 + 64 + f + 2] = q.z; red[wv * 128 + 64 + f + 3] = q.w;
  }
  __syncthreads();
  if (tid < 128) {
    float v = red[tid] + red[128 + tid] + red[256 + tid] + red[384 + tid];
    atomicAdd(&stats2[tid], v);
  }
}

__global__ void finalize2_k(const float* __restrict__ stats2,
                            const float* __restrict__ g,
                            const float* __restrict__ be,
                            float* __restrict__ ab2) {
  int f = threadIdx.x;   // 64
  float mu = stats2[f] * (1.f / N_NODES);
  float var = stats2[64 + f] * (1.f / N_NODES) - mu * mu;
  float a = g[f] * rsqrtf(var + 1e-5f);
  ab2[f] = a;
  ab2[64 + f] = be[f] - mu * a;
}

__launch_bounds__(256)
__global__ void out_k(const float* __restrict__ atom,
                      const float* __restrict__ ab2,
                      float* __restrict__ out) {
  int gid = blockIdx.x * 256 + threadIdx.x;
  int stride = gridDim.x * 256;
  for (int i = gid; i < N_NODES * 16; i += stride) {
    float4 u = ((const float4*)out)[i];
    float4 x = ((const float4*)atom)[i];
    int f = (i & 15) * 4;
    float4 r;
    r.x = softplus_f(x.x + u.x * ab2[f + 0] + ab2[64 + f + 0]);
    r.y = softplus_f(x.y + u.y * ab2[f + 1] + ab2[64 + f + 1]);
    r.z = softplus_f(x.z + u.z * ab2[f + 2] + ab2[64 + f + 2]);
    r.w = softplus_f(x.w + u.w * ab2[f + 3] + ab2[64 + f + 3]);
    ((float4*)out)[i] = r;
  }
}

// ---------------- scatter path (round-5 known-good, mid fallback) ------------
__launch_bounds__(256)
__global__ void scatter_k(const unsigned short* __restrict__ zt,
                          const int* __restrict__ edst,
                          const float* __restrict__ ab,
                          float* __restrict__ out) {
  int gid = blockIdx.x * 256 + threadIdx.x;  // (tile, c, r8)
  int r8 = gid & 7;
  int c = (gid >> 3) & 63;
  int tile = gid >> 9;
  const unsigned short* fb = zt + ((size_t)tile * 128 + c) * 64 + r8 * 8;
  const unsigned short* gb = fb + 64 * 64;
  s16x8 f8 = *(const s16x8*)fb;
  s16x8 g8 = *(const s16x8*)gb;
  float af = ab[c], cf = ab[128 + c];
  float ag = ab[64 + c], cg = ab[192 + c];
  int4 d0 = *(const int4*)(edst + tile * 64 + r8 * 8);
  int4 d1 = *(const int4*)(edst + tile * 64 + r8 * 8 + 4);
  int dsts[8] = {d0.x, d0.y, d0.z, d0.w, d1.x, d1.y, d1.z, d1.w};
  #pragma unroll
  for (int i = 0; i < 8; ++i) {
    float f = af * h2f((unsigned short)f8[i]) + cf;
    float g = ag * h2f((unsigned short)g8[i]) + cg;
    float m = sigmoid_f(f) * softplus_f(g);
    atomicAdd(out + (size_t)dsts[i] * ATOMF + c, m);
  }
}

// ================= FALLBACK (round-1 two-pass path, known-good) ==============
template<int PASS>
__launch_bounds__(256, 2)
__global__ void edge_pass(const float* __restrict__ atom,
                          const float* __restrict__ nbr,
                          const int* __restrict__ esrc,
                          const int* __restrict__ edst,
                          const float* __restrict__ W,
                          const float* __restrict__ bvec,
                          float* __restrict__ stats,
                          const float* __restrict__ ab,
                          float* __restrict__ upd) {
  __shared__ short Wl[DOUT * LDW];
  __shared__ short Tl[EPB * LDW];
  __shared__ int eix[2 * EPB];

  const int tid = threadIdx.x;
  const int lane = tid & 63;
  const int wv = tid >> 6;
  const int l15 = lane & 15;
  const int lg = lane >> 4;

  for (int i = tid; i < DIN * DOUT; i += 256) {
    int k = i >> 7, n = i & 127;
    Wl[n * LDW + k] = f2bf(W[i]);
  }
  float bcol[8], acol[8], ccol[8];
  #pragma unroll
  for (int j = 0; j < 8; ++j) {
    int n = j * 16 + l15;
    bcol[j] = bvec[n];
    if constexpr (PASS == 1) { acol[j] = ab[n]; ccol[j] = ab[DOUT + n]; }
    else { acol[j] = 0.f; ccol[j] = 0.f; }
  }
  float fsum[8], fsq[8];
  #pragma unroll
  for (int j = 0; j < 8; ++j) { fsum[j] = 0.f; fsq[j] = 0.f; }

  for (int tile = blockIdx.x; tile < NTILES; tile += gridDim.x) {
    const int e0 = tile * EPB;
    __syncthreads();
    if (tid < EPB) eix[tid] = esrc[e0 + tid];
    else if (tid < 2 * EPB) eix[tid] = edst[e0 + tid - EPB];
    __syncthreads();
    for (int i = tid; i < EPB * 96; i += 256) {
      int row = i / 96;
      int cl = (i - row * 96) * 2;
      const float* p;
      if (cl < 64)       p = atom + (size_t)eix[row] * 64 + cl;
      else if (cl < 128) p = atom + (size_t)eix[EPB + row] * 64 + (cl - 64);
      else               p = nbr + (size_t)(e0 + row) * 64 + (cl - 128);
      float2 v = *(const float2*)p;
      unsigned pk = (unsigned)(unsigned short)f2bf(v.x)
                  | ((unsigned)(unsigned short)f2bf(v.y) << 16);
      *(unsigned*)&Tl[row * LDW + cl] = pk;
    }
    __syncthreads();
    f32x4 acc[8] = {};
    const int abase = (wv * 16 + l15) * LDW + lg * 8;
    #pragma unroll
    for (int kk = 0; kk < 6; ++kk) {
      bf16x8 afr = *(const bf16x8*)&Tl[abase + kk * 32];
      #pragma unroll
      for (int j = 0; j < 8; ++j) {
        bf16x8 bfr = *(const bf16x8*)&Wl[(j * 16 + l15) * LDW + lg * 8 + kk * 32];
        acc[j] = __builtin_amdgcn_mfma_f32_16x16x32_bf16(afr, bfr, acc[j], 0, 0, 0);
      }
    }
    if constexpr (PASS == 0) {
      #pragma unroll
      for (int j = 0; j < 8; ++j)
        #pragma unroll
        for (int r = 0; r < 4; ++r) {
          float z = acc[j][r] + bcol[j];
          fsum[j] += z; fsq[j] += z * z;
        }
    } else {
      #pragma unroll
      for (int r = 0; r < 4; ++r) {
        int row = wv * 16 + lg * 4 + r;
        int d = eix[EPB + row];
        float* urow = upd + (size_t)d * 64;
        #pragma unroll
        for (int j = 0; j < 4; ++j) {
          float f = (acc[j][r] + bcol[j]) * acol[j] + ccol[j];
          float g = (acc[j + 4][r] + bcol[j + 4]) * acol[j + 4] + ccol[j + 4];
          atomicAdd(&urow[j * 16 + l15], sigmoid_f(f) * softplus_f(g));
        }
      }
    }
  }
  if constexpr (PASS == 0) {
    #pragma unroll
    for (int j = 0; j < 8; ++j) {
      fsum[j] += __shfl_xor(fsum[j], 16, 64);
      fsum[j] += __shfl_xor(fsum[j], 32, 64);
      fsq[j]  += __shfl_xor(fsq[j], 16, 64);
      fsq[j]  += __shfl_xor(fsq[j], 32, 64);
    }
    __syncthreads();
    float* redf = (float*)Tl;
    if (lane < 16) {
      #pragma unroll
      for (int j = 0; j < 8; ++j) {
        redf[wv * 256 + j * 16 + lane] = fsum[j];
        redf[wv * 256 + 128 + j * 16 + lane] = fsq[j];
      }
    }
    __syncthreads();
    float s = redf[tid] + redf[256 + tid] + redf[512 + tid] + redf[768 + tid];
    atomicAdd(&stats[tid], s);
  }
}

// =============================================================================
extern "C" void kernel_launch(void* const* d_in, const int* in_sizes, int n_in,
                              void* d_out, int out_size, void* d_ws, size_t ws_size,
                              hipStream_t stream) {
  const float* atom = (const float*)d_in[0];
  const float* nbr  = (const float*)d_in[1];
  const int*   esrc = (const int*)d_in[2];
  const int*   edst = (const int*)d_in[3];
  const float* W    = (const float*)d_in[4];
  const float* bvec = (const float*)d_in[5];
  const float* g1   = (const float*)d_in[6];
  const float* b1   = (const float*)d_in[7];
  const float* g2   = (const float*)d_in[8];
  const float* b2   = (const float*)d_in[9];
  float* out = (float*)d_out;
  char* ws = (char*)d_ws;

  float* stats1 = (float*)ws;          // [256]
  float* ab1    = stats1 + 256;        // [256]
  float* stats2 = stats1 + 512;        // [128]
  float* ab2    = stats1 + 640;        // [128]

  const size_t OFF_ATOM = 4096;
  const size_t SZ_ATOM  = (size_t)N_NODES * ATOMF * 2;    //   6.4 MB
  const size_t OFF_NBR  = OFF_ATOM + SZ_ATOM;             // msg overlays this
  const size_t SZ_NBR   = (size_t)N_EDGES * ATOMF * 2;    // 102.4 MB
  const size_t OFF_ZT   = OFF_NBR + SZ_NBR;
  const size_t SZ_ZT    = (size_t)N_EDGES * DOUT * 2;     // 204.8 MB
  const size_t NEED_OLD = OFF_ZT + SZ_ZT;                 // ~313.6 MB
  const size_t OFF_PERM = NEED_OLD;
  const size_t SZ_PERM  = (size_t)N_EDGES * 4;            //   3.2 MB
  const size_t OFF_DEG  = OFF_PERM + SZ_PERM;
  const size_t OFF_RP   = OFF_DEG + N_NODES * 4;
  const size_t OFF_CUR  = OFF_RP + (N_NODES + 1) * 4 + 12;   // keep 16B align
  const size_t NEED_NEW = OFF_CUR + N_NODES * 4;          // ~317.8 MB

  hipMemsetAsync(stats1, 0, 768 * sizeof(float), stream);

  if (ws_size >= NEED_NEW) {
    unsigned short* atom_bf = (unsigned short*)(ws + OFF_ATOM);
    unsigned short* nbr_bf  = (unsigned short*)(ws + OFF_NBR);
    unsigned short* zt      = (unsigned short*)(ws + OFF_ZT);
    unsigned short* msg     = nbr_bf;          // overlay: nbr_bf dead after GEMM
    int* iperm  = (int*)(ws + OFF_PERM);
    int* deg    = (int*)(ws + OFF_DEG);
    int* rowptr = (int*)(ws + OFF_RP);
    int* cursor = (int*)(ws + OFF_CUR);

    hipMemsetAsync(deg, 0, N_NODES * sizeof(int), stream);
    hist_k<<<(N_EDGES + 255) / 256, 256, 0, stream>>>(edst, deg);
    scan_k<<<1, 1024, 0, stream>>>(deg, rowptr, cursor);
    fill_k<<<(N_EDGES + 255) / 256, 256, 0, stream>>>(edst, cursor, iperm);

    precvt_k<<<2048, 256, 0, stream>>>(atom, nbr, atom_bf, nbr_bf);
    edge_gemm<<<1536, 256, 0, stream>>>(atom_bf, nbr_bf, esrc, edst, W, stats1, zt);
    finalize1_k<<<1, 128, 0, stream>>>(stats1, g1, b1, ab1);

    msg_k<<<NTILES, 256, 0, stream>>>(zt, ab1, iperm, msg);
    gather_k<<<(N_NODES + 3) / 4, 256, 0, stream>>>(msg, rowptr, out);
  } else if (ws_size >= NEED_OLD) {
    unsigned short* atom_bf = (unsigned short*)(ws + OFF_ATOM);
    unsigned short* nbr_bf  = (unsigned short*)(ws + OFF_NBR);
    unsigned short* zt      = (unsigned short*)(ws + OFF_ZT);
    hipMemsetAsync(out, 0, (size_t)N_NODES * 64 * sizeof(float), stream);
    precvt_k<<<2048, 256, 0, stream>>>(atom, nbr, atom_bf, nbr_bf);
    edge_gemm<<<1536, 256, 0, stream>>>(atom_bf, nbr_bf, esrc, edst, W, stats1, zt);
    finalize1_k<<<1, 128, 0, stream>>>(stats1, g1, b1, ab1);
    scatter_k<<<25000, 256, 0, stream>>>(zt, edst, ab1, out);
  } else {
    hipMemsetAsync(out, 0, (size_t)N_NODES * 64 * sizeof(float), stream);
    edge_pass<0><<<512, 256, 0, stream>>>(atom, nbr, esrc, edst, W, bvec,
                                          stats1, nullptr, nullptr);
    finalize1_k<<<1, 128, 0, stream>>>(stats1, g1, b1, ab1);
    edge_pass<1><<<512, 256, 0, stream>>>(atom, nbr, esrc, edst, W, bvec,
                                          nullptr, ab1, out);
  }

  stats2_k<<<512, 256, 0, stream>>>(out, stats2);
  finalize2_k<<<1, 64, 0, stream>>>(stats2, g2, b2, ab2);
  out_k<<<512, 256, 0, stream>>>(atom, ab2, out);
}

// Round 9
// 535.737 us; speedup vs baseline: 1.4030x; 1.4030x over previous
//
#include <hip/hip_runtime.h>
#include <hip/hip_fp16.h>
#include <math.h>

#define N_NODES 50000
#define N_EDGES 800000
#define ATOMF 64
#define DIN 192
#define DOUT 128
#define EPB 64
#define NTILES (N_EDGES / EPB)   // 12500
#define LDW 200                  // LDS row stride in bf16 (192 data + 8 pad = 25 x 16B chunks)
#define NSLOT (EPB * 25)         // 1600 16B-chunks per tile

typedef __attribute__((ext_vector_type(8))) short bf16x8;
typedef __attribute__((ext_vector_type(8))) short s16x8;
typedef __attribute__((ext_vector_type(4))) float f32x4;

__device__ __forceinline__ short f2bf(float f) {
  unsigned u = __float_as_uint(f);
  u += 0x7fffu + ((u >> 16) & 1u);   // RNE
  return (short)(u >> 16);
}
__device__ __forceinline__ float bf2f(unsigned short u) {
  return __uint_as_float(((unsigned)u) << 16);
}
__device__ __forceinline__ unsigned short f2h(float f) {
  __half h = __float2half_rn(f);     // v_cvt_f16_f32 (RNE)
  return *(unsigned short*)&h;
}
__device__ __forceinline__ float h2f(unsigned short u) {
  __half h = *(__half*)&u;
  return __half2float(h);            // v_cvt_f32_f16
}
__device__ __forceinline__ float softplus_f(float x) {
  return fmaxf(x, 0.f) + log1pf(__expf(-fabsf(x)));
}
__device__ __forceinline__ float sigmoid_f(float x) {
  return 1.f / (1.f + __expf(-x));
}
// fast variants for the 51.2M-element msg pass (err ~1e-6, threshold 0.24)
__device__ __forceinline__ float fast_sigmoid(float x) {
  return __builtin_amdgcn_rcpf(1.f + __expf(-x));
}
__device__ __forceinline__ float fast_softplus(float x) {
  return fmaxf(x, 0.f) + __logf(1.f + __expf(-fabsf(x)));
}

#define GLOAD16(g, l)                                                          \
  __builtin_amdgcn_global_load_lds(                                            \
      (const __attribute__((address_space(1))) void*)(g),                      \
      (__attribute__((address_space(3))) void*)(l), 16, 0, 0)

// ---------------- fp32 -> bf16 pre-convert (atom table + nbr features) -------
__launch_bounds__(256)
__global__ void precvt_k(const float* __restrict__ atom,
                         const float* __restrict__ nbr,
                         unsigned short* __restrict__ atom_bf,
                         unsigned short* __restrict__ nbr_bf) {
  const int NA = N_NODES * ATOMF / 8;        // 400000 chunks of 8
  const int NB = N_EDGES * ATOMF / 8;        // 6400000
  int stride = gridDim.x * blockDim.x;
  for (int i = blockIdx.x * blockDim.x + threadIdx.x; i < NA + NB; i += stride) {
    const float* s;
    unsigned short* d;
    if (i < NA) { s = atom + (size_t)i * 8; d = atom_bf + (size_t)i * 8; }
    else        { s = nbr + (size_t)(i - NA) * 8; d = nbr_bf + (size_t)(i - NA) * 8; }
    float4 a = ((const float4*)s)[0];
    float4 b = ((const float4*)s)[1];
    s16x8 t;
    t[0] = f2bf(a.x); t[1] = f2bf(a.y); t[2] = f2bf(a.z); t[3] = f2bf(a.w);
    t[4] = f2bf(b.x); t[5] = f2bf(b.y); t[6] = f2bf(b.z); t[7] = f2bf(b.w);
    *(s16x8*)d = t;
  }
}

// ---------------- CSR build: histogram -> scan -> fill (inverse perm) --------
__launch_bounds__(256)
__global__ void hist_k(const int* __restrict__ edst, int* __restrict__ deg) {
  int gid = blockIdx.x * 256 + threadIdx.x;
  if (gid < N_EDGES) atomicAdd(&deg[edst[gid]], 1);
}

__launch_bounds__(1024)
__global__ void scan_k(const int* __restrict__ deg,
                       int* __restrict__ rowptr,
                       int* __restrict__ cursor) {
  __shared__ int wsum[16];
  const int tid = threadIdx.x;
  const int lane = tid & 63, wv = tid >> 6;
  int base = 0;
  for (int c0 = 0; c0 < N_NODES; c0 += 1024) {
    int i = c0 + tid;
    int v = (i < N_NODES) ? deg[i] : 0;
    int s = v;
    #pragma unroll
    for (int d = 1; d < 64; d <<= 1) {
      int t = __shfl_up(s, d, 64);
      if (lane >= d) s += t;
    }
    if (lane == 63) wsum[wv] = s;
    __syncthreads();
    if (wv == 0 && lane < 16) {
      int ws = wsum[lane];
      #pragma unroll
      for (int d = 1; d < 16; d <<= 1) {
        int t = __shfl_up(ws, d, 64);
        if (lane >= d) ws += t;
      }
      wsum[lane] = ws;
    }
    __syncthreads();
    int wbase = wv ? wsum[wv - 1] : 0;
    int excl = base + wbase + s - v;
    if (i < N_NODES) { rowptr[i] = excl; cursor[i] = excl; }
    int tot = wsum[15];
    __syncthreads();   // everyone done reading wsum before next iter overwrites
    base += tot;
  }
  if (tid == 0) rowptr[N_NODES] = base;   // == N_EDGES
}

__launch_bounds__(256)
__global__ void fill_k(const int* __restrict__ edst,
                       int* __restrict__ cursor,
                       int* __restrict__ iperm) {
  int gid = blockIdx.x * 256 + threadIdx.x;
  if (gid < N_EDGES) {
    int pos = atomicAdd(&cursor[edst[gid]], 1);
    iperm[gid] = pos;          // inverse perm: edge -> CSR slot
  }
}

// ---------------- single edge pass: gather -> MFMA -> z store + stats --------
// zt layout: zt[tile][col(128)][row(64)] fp16 (tile-transposed for wide stores)
//
// Schedule: guide §5.5 T3-minimum double-buffer with EXPLICIT vmcnt(0) drain
// before each barrier (inline asm). Rationale: global_load_lds has no dest
// register, so the compiler's waitcnt insertion can miss in-flight LDS-DMA
// across the loop back-edge (rounds 2-4, 8 raced; round 7 only passed because
// spill-reload waits incidentally drained it). Explicit drain closes the hole
// at ISA level: every wave completes ALL its vmem (incl. LDS-DMA) before the
// barrier; a buffer is staged only after a barrier post-dating its reads.
__device__ __forceinline__ void stage_tile(const unsigned short* __restrict__ atom_bf,
                                           const unsigned short* __restrict__ nbr_bf,
                                           const int* __restrict__ esrc,
                                           const int* __restrict__ edst,
                                           int e0, unsigned short* lbase,
                                           const int* g_enc, int wv) {
  #pragma unroll
  for (int it = 0; it < 7; ++it) {
    if (it * 256 + wv * 64 < NSLOT) {        // wave-uniform tail guard
      int e = g_enc[it];
      int row = e & 255;
      int coff = (e >> 8) & 255;
      int sel = e >> 16;
      const unsigned short* src;
      if (sel < 2) {
        const int* ip = sel ? edst : esrc;
        int idx = ip[e0 + row];
        src = atom_bf + (size_t)idx * ATOMF + coff;
      } else {
        src = nbr_bf + (size_t)(e0 + row) * ATOMF + coff;
      }
      GLOAD16(src, lbase + (size_t)(it * 256 + wv * 64) * 8);
    }
  }
}

__launch_bounds__(256, 4)
__global__ void edge_gemm(const unsigned short* __restrict__ atom_bf,
                          const unsigned short* __restrict__ nbr_bf,
                          const int* __restrict__ esrc,
                          const int* __restrict__ edst,
                          const float* __restrict__ W,
                          float* __restrict__ stats,
                          unsigned short* __restrict__ zt) {
  __shared__ unsigned short Tl[2][EPB * LDW];   // 2 x 25600 B -> 3 blocks/CU

  const int tid = threadIdx.x;
  const int lane = tid & 63;
  const int wv = tid >> 6;
  const int l15 = lane & 15;
  const int lg = lane >> 4;
  const int colF = wv * 16 + l15;            // filter column
  const int colC = colF + 64;                // core column

  // W fragments in registers: wf[cg][kk][jj] = W[kk*32+lg*8+jj][cg*64+colF]
  bf16x8 wf[2][6];
  #pragma unroll
  for (int cg = 0; cg < 2; ++cg) {
    #pragma unroll
    for (int kk = 0; kk < 6; ++kk) {
      bf16x8 t;
      #pragma unroll
      for (int jj = 0; jj < 8; ++jj)
        t[jj] = f2bf(W[(size_t)(kk * 32 + lg * 8 + jj) * 128 + cg * 64 + colF]);
      wf[cg][kk] = t;
    }
  }

  // slot s = it*256+tid -> (row = s/25, w = s%25)
  // w<8: atom[src]; w<16: atom[dst]; w<24: nbr; w==24: pad (harmless load)
  int g_enc[7];
  #pragma unroll
  for (int it = 0; it < 7; ++it) {
    int s = it * 256 + tid;
    if (s >= NSLOT) s = 0;                   // dead slot (wave guard at use)
    int row = s / 25;
    int w = s - row * 25;
    int sel, coff;
    if (w < 8)       { sel = 0; coff = w * 8; }
    else if (w < 16) { sel = 1; coff = (w - 8) * 8; }
    else             { sel = 2; coff = (w < 24 ? (w - 16) * 8 : 0); }
    g_enc[it] = row | (coff << 8) | (sel << 16);
  }

  float fs[2] = {0.f, 0.f}, fq[2] = {0.f, 0.f};

  int cur = 0;
  int t0 = blockIdx.x;
  if (t0 < NTILES)
    stage_tile(atom_bf, nbr_bf, esrc, edst, t0 * EPB, &Tl[0][0], g_enc, wv);

  for (int tile = t0; tile < NTILES; tile += gridDim.x) {
    // EXPLICIT drain: my LDS-DMA (and stores) complete before the barrier;
    // after the barrier every wave's staged data is in LDS.
    asm volatile("s_waitcnt vmcnt(0)" ::: "memory");
    __syncthreads();
    __builtin_amdgcn_sched_barrier(0);       // pin ds_reads below the barrier

    int nxt = tile + gridDim.x;
    if (nxt < NTILES)                        // overlap: stage other buffer now
      stage_tile(atom_bf, nbr_bf, esrc, edst, nxt * EPB, &Tl[cur ^ 1][0], g_enc, wv);

    f32x4 acc[2][4] = {};
    #pragma unroll
    for (int rg = 0; rg < 4; ++rg) {
      #pragma unroll
      for (int kk = 0; kk < 6; ++kk) {
        bf16x8 a = *(const bf16x8*)&Tl[cur][(rg * 16 + l15) * LDW + kk * 32 + lg * 8];
        acc[0][rg] = __builtin_amdgcn_mfma_f32_16x16x32_bf16(a, wf[0][kk], acc[0][rg], 0, 0, 0);
        acc[1][rg] = __builtin_amdgcn_mfma_f32_16x16x32_bf16(a, wf[1][kk], acc[1][rg], 0, 0, 0);
      }
    }

    // epilogue: stats + fp16 pack + 8B stores; D: row = rg*16 + lg*4 + r
    #pragma unroll
    for (int cg = 0; cg < 2; ++cg) {
      unsigned short* zb = zt + ((size_t)tile * 128 + cg * 64 + colF) * 64 + lg * 4;
      #pragma unroll
      for (int rg = 0; rg < 4; ++rg) {
        float z0 = acc[cg][rg][0], z1 = acc[cg][rg][1];
        float z2 = acc[cg][rg][2], z3 = acc[cg][rg][3];
        fs[cg] += (z0 + z1) + (z2 + z3);
        fq[cg] += z0 * z0 + z1 * z1 + z2 * z2 + z3 * z3;
        uint2 p;
        p.x = (unsigned)f2h(z0) | ((unsigned)f2h(z1) << 16);
        p.y = (unsigned)f2h(z2) | ((unsigned)f2h(z3) << 16);
        *(uint2*)(zb + rg * 16) = p;
      }
    }
    cur ^= 1;
  }

  #pragma unroll
  for (int cg = 0; cg < 2; ++cg) {
    fs[cg] += __shfl_xor(fs[cg], 16, 64); fs[cg] += __shfl_xor(fs[cg], 32, 64);
    fq[cg] += __shfl_xor(fq[cg], 16, 64); fq[cg] += __shfl_xor(fq[cg], 32, 64);
  }
  if (lane < 16) {
    atomicAdd(&stats[colF], fs[0]);
    atomicAdd(&stats[colC], fs[1]);
    atomicAdd(&stats[128 + colF], fq[0]);
    atomicAdd(&stats[128 + colC], fq[1]);
  }
}

// ---------------- BN1 finalize (b_full == 0; bias cancels inside BN anyway) --
__global__ void finalize1_k(const float* __restrict__ stats,
                            const float* __restrict__ g,
                            const float* __restrict__ be,
                            float* __restrict__ ab) {
  int n = threadIdx.x;   // 128
  float mu = stats[n] * (1.f / N_EDGES);
  float var = stats[128 + n] * (1.f / N_EDGES) - mu * mu;
  float a = g[n] * rsqrtf(var + 1e-5f);
  ab[n] = a;
  ab[128 + n] = be[n] - mu * a;
}

// ---------------- gate -> msg in CSR order (via LDS transpose) ---------------
// one block per tile: read zt[tile] (col-major), write msg[iperm[e]][64]
__launch_bounds__(256)
__global__ void msg_k(const unsigned short* __restrict__ zt,
                      const float* __restrict__ ab,
                      const int* __restrict__ iperm,
                      unsigned short* __restrict__ msg) {
  __shared__ unsigned short ml[64][72];      // +8 pad
  const int tile = blockIdx.x;
  const int tid = threadIdx.x;
  const int c = tid & 63;                    // filter col (core = c+64)
  const int rg = tid >> 6;                   // rows rg*16 .. +15
  const unsigned short* fb = zt + ((size_t)tile * 128 + c) * 64 + rg * 16;
  const unsigned short* gb = fb + (size_t)64 * 64;
  s16x8 f0 = *(const s16x8*)fb;
  s16x8 f1 = *(const s16x8*)(fb + 8);
  s16x8 g0 = *(const s16x8*)gb;
  s16x8 g1 = *(const s16x8*)(gb + 8);
  float af = ab[c], cf = ab[128 + c];
  float ag = ab[64 + c], cg = ab[192 + c];
  #pragma unroll
  for (int k = 0; k < 16; ++k) {
    unsigned short fu = (unsigned short)(k < 8 ? f0[k] : f1[k - 8]);
    unsigned short gu = (unsigned short)(k < 8 ? g0[k] : g1[k - 8]);
    float f = af * h2f(fu) + cf;
    float g = ag * h2f(gu) + cg;
    ml[rg * 16 + k][c] = f2h(fast_sigmoid(f) * fast_softplus(g));
  }
  const int r = tid >> 2;
  const int pos = iperm[tile * 64 + r];      // CSR slot for this edge row
  __syncthreads();
  const int cq = (tid & 3) * 16;
  s16x8 o0, o1;
  #pragma unroll
  for (int k = 0; k < 8; ++k) { o0[k] = ml[r][cq + k]; o1[k] = ml[r][cq + 8 + k]; }
  unsigned short* ob = msg + (size_t)pos * 64 + cq;
  *(s16x8*)ob = o0;
  *(s16x8*)(ob + 8) = o1;
}

// ---------------- gather: one wave per node, contiguous CSR rows -------------
__launch_bounds__(256)
__global__ void gather_k(const unsigned short* __restrict__ msg,
                         const int* __restrict__ rowptr,
                         float* __restrict__ out) {
  int n = blockIdx.x * 4 + (threadIdx.x >> 6);
  if (n >= N_NODES) return;
  int lane = threadIdx.x & 63;
  int s = rowptr[n], e = rowptr[n + 1];
  float acc = 0.f;
  for (int i = s; i < e; ++i)
    acc += h2f(msg[(size_t)i * 64 + lane]);
  out[(size_t)n * 64 + lane] = acc;
}

// ---------------- node-side stats / finalize / output ------------------------
__launch_bounds__(256)
__global__ void stats2_k(const float* __restrict__ upd, float* __restrict__ stats2) {
  int tid = threadIdx.x;
  int gid = blockIdx.x * 256 + tid;
  int stride = gridDim.x * 256;
  float4 s = make_float4(0.f, 0.f, 0.f, 0.f);
  float4 q = make_float4(0.f, 0.f, 0.f, 0.f);
  for (int i = gid; i < N_NODES * 16; i += stride) {
    float4 v = ((const float4*)upd)[i];
    s.x += v.x; s.y += v.y; s.z += v.z; s.w += v.w;
    q.x += v.x * v.x; q.y += v.y * v.y; q.z += v.z * v.z; q.w += v.w * v.w;
  }
  int lane = tid & 63;
  int wv = tid >> 6;
  s.x += __shfl_xor(s.x, 16, 64); s.x += __shfl_xor(s.x, 32, 64);
  s.y += __shfl_xor(s.y, 16, 64); s.y += __shfl_xor(s.y, 32, 64);
  s.z += __shfl_xor(s.z, 16, 64); s.z += __shfl_xor(s.z, 32, 64);
  s.w += __shfl_xor(s.w, 16, 64); s.w += __shfl_xor(s.w, 32, 64);
  q.x += __shfl_xor(q.x, 16, 64); q.x += __shfl_xor(q.x, 32, 64);
  q.y += __shfl_xor(q.y, 16, 64); q.y += __shfl_xor(q.y, 32, 64);
  q.z += __shfl_xor(q.z, 16, 64); q.z += __shfl_xor(q.z, 32, 64);
  q.w += __shfl_xor(q.w, 16, 64); q.w += __shfl_xor(q.w, 32, 64);
  __shared__ float red[4 * 128];
  if (lane < 16) {
    int f = lane * 4;
    red[wv * 128 + f + 0] = s.x; red[wv * 128 + f + 1] = s.y;
    red[wv * 128 + f + 2] = s.z; red[wv * 128 + f + 3] = s.w;
    red[wv * 128 + 64 + f + 0] = q.x; red[wv * 128 + 64 + f + 1] = q.y;
    red[wv * 128 + 64 + f + 2] = q.z; red[wv * 128 + 64 + f + 3] = q.w;
  }
  __syncthreads();
  if (tid < 128) {
    float v = red[tid] + red[128 + tid] + red[256 + tid] + red[384 + tid];
    atomicAdd(&stats2[tid], v);
  }
}

__global__ void finalize2_k(const float* __restrict__ stats2,
                            const float* __restrict__ g,
                            const float* __restrict__ be,
                            float* __restrict__ ab2) {
  int f = threadIdx.x;   // 64
  float mu = stats2[f] * (1.f / N_NODES);
  float var = stats2[64 + f] * (1.f / N_NODES) - mu * mu;
  float a = g[f] * rsqrtf(var + 1e-5f);
  ab2[f] = a;
  ab2[64 + f] = be[f] - mu * a;
}

__launch_bounds__(256)
__global__ void out_k(const float* __restrict__ atom,
                      const float* __restrict__ ab2,
                      float* __restrict__ out) {
  int gid = blockIdx.x * 256 + threadIdx.x;
  int stride = gridDim.x * 256;
  for (int i = gid; i < N_NODES * 16; i += stride) {
    float4 u = ((const float4*)out)[i];
    float4 x = ((const float4*)atom)[i];
    int f = (i & 15) * 4;
    float4 r;
    r.x = softplus_f(x.x + u.x * ab2[f + 0] + ab2[64 + f + 0]);
    r.y = softplus_f(x.y + u.y * ab2[f + 1] + ab2[64 + f + 1]);
    r.z = softplus_f(x.z + u.z * ab2[f + 2] + ab2[64 + f + 2]);
    r.w = softplus_f(x.w + u.w * ab2[f + 3] + ab2[64 + f + 3]);
    ((float4*)out)[i] = r;
  }
}

// ---------------- scatter path (round-5 known-good, mid fallback) ------------
__launch_bounds__(256)
__global__ void scatter_k(const unsigned short* __restrict__ zt,
                          const int* __restrict__ edst,
                          const float* __restrict__ ab,
                          float* __restrict__ out) {
  int gid = blockIdx.x * 256 + threadIdx.x;  // (tile, c, r8)
  int r8 = gid & 7;
  int c = (gid >> 3) & 63;
  int tile = gid >> 9;
  const unsigned short* fb = zt + ((size_t)tile * 128 + c) * 64 + r8 * 8;
  const unsigned short* gb = fb + 64 * 64;
  s16x8 f8 = *(const s16x8*)fb;
  s16x8 g8 = *(const s16x8*)gb;
  float af = ab[c], cf = ab[128 + c];
  float ag = ab[64 + c], cg = ab[192 + c];
  int4 d0 = *(const int4*)(edst + tile * 64 + r8 * 8);
  int4 d1 = *(const int4*)(edst + tile * 64 + r8 * 8 + 4);
  int dsts[8] = {d0.x, d0.y, d0.z, d0.w, d1.x, d1.y, d1.z, d1.w};
  #pragma unroll
  for (int i = 0; i < 8; ++i) {
    float f = af * h2f((unsigned short)f8[i]) + cf;
    float g = ag * h2f((unsigned short)g8[i]) + cg;
    float m = sigmoid_f(f) * softplus_f(g);
    atomicAdd(out + (size_t)dsts[i] * ATOMF + c, m);
  }
}

// ================= FALLBACK (round-1 two-pass path, known-good) ==============
template<int PASS>
__launch_bounds__(256, 2)
__global__ void edge_pass(const float* __restrict__ atom,
                          const float* __restrict__ nbr,
                          const int* __restrict__ esrc,
                          const int* __restrict__ edst,
                          const float* __restrict__ W,
                          const float* __restrict__ bvec,
                          float* __restrict__ stats,
                          const float* __restrict__ ab,
                          float* __restrict__ upd) {
  __shared__ short Wl[DOUT * LDW];
  __shared__ short Tl[EPB * LDW];
  __shared__ int eix[2 * EPB];

  const int tid = threadIdx.x;
  const int lane = tid & 63;
  const int wv = tid >> 6;
  const int l15 = lane & 15;
  const int lg = lane >> 4;

  for (int i = tid; i < DIN * DOUT; i += 256) {
    int k = i >> 7, n = i & 127;
    Wl[n * LDW + k] = f2bf(W[i]);
  }
  float bcol[8], acol[8], ccol[8];
  #pragma unroll
  for (int j = 0; j < 8; ++j) {
    int n = j * 16 + l15;
    bcol[j] = bvec[n];
    if constexpr (PASS == 1) { acol[j] = ab[n]; ccol[j] = ab[DOUT + n]; }
    else { acol[j] = 0.f; ccol[j] = 0.f; }
  }
  float fsum[8], fsq[8];
  #pragma unroll
  for (int j = 0; j < 8; ++j) { fsum[j] = 0.f; fsq[j] = 0.f; }

  for (int tile = blockIdx.x; tile < NTILES; tile += gridDim.x) {
    const int e0 = tile * EPB;
    __syncthreads();
    if (tid < EPB) eix[tid] = esrc[e0 + tid];
    else if (tid < 2 * EPB) eix[tid] = edst[e0 + tid - EPB];
    __syncthreads();
    for (int i = tid; i < EPB * 96; i += 256) {
      int row = i / 96;
      int cl = (i - row * 96) * 2;
      const float* p;
      if (cl < 64)       p = atom + (size_t)eix[row] * 64 + cl;
      else if (cl < 128) p = atom + (size_t)eix[EPB + row] * 64 + (cl - 64);
      else               p = nbr + (size_t)(e0 + row) * 64 + (cl - 128);
      float2 v = *(const float2*)p;
      unsigned pk = (unsigned)(unsigned short)f2bf(v.x)
                  | ((unsigned)(unsigned short)f2bf(v.y) << 16);
      *(unsigned*)&Tl[row * LDW + cl] = pk;
    }
    __syncthreads();
    f32x4 acc[8] = {};
    const int abase = (wv * 16 + l15) * LDW + lg * 8;
    #pragma unroll
    for (int kk = 0; kk < 6; ++kk) {
      bf16x8 afr = *(const bf16x8*)&Tl[abase + kk * 32];
      #pragma unroll
      for (int j = 0; j < 8; ++j) {
        bf16x8 bfr = *(const bf16x8*)&Wl[(j * 16 + l15) * LDW + lg * 8 + kk * 32];
        acc[j] = __builtin_amdgcn_mfma_f32_16x16x32_bf16(afr, bfr, acc[j], 0, 0, 0);
      }
    }
    if constexpr (PASS == 0) {
      #pragma unroll
      for (int j = 0; j < 8; ++j)
        #pragma unroll
        for (int r = 0; r < 4; ++r) {
          float z = acc[j][r] + bcol[j];
          fsum[j] += z; fsq[j] += z * z;
        }
    } else {
      #pragma unroll
      for (int r = 0; r < 4; ++r) {
        int row = wv * 16 + lg * 4 + r;
        int d = eix[EPB + row];
        float* urow = upd + (size_t)d * 64;
        #pragma unroll
        for (int j = 0; j < 4; ++j) {
          float f = (acc[j][r] + bcol[j]) * acol[j] + ccol[j];
          float g = (acc[j + 4][r] + bcol[j + 4]) * acol[j + 4] + ccol[j + 4];
          atomicAdd(&urow[j * 16 + l15], sigmoid_f(f) * softplus_f(g));
        }
      }
    }
  }
  if constexpr (PASS == 0) {
    #pragma unroll
    for (int j = 0; j < 8; ++j) {
      fsum[j] += __shfl_xor(fsum[j], 16, 64);
      fsum[j] += __shfl_xor(fsum[j], 32, 64);
      fsq[j]  += __shfl_xor(fsq[j], 16, 64);
      fsq[j]  += __shfl_xor(fsq[j], 32, 64);
    }
    __syncthreads();
    float* redf = (float*)Tl;
    if (lane < 16) {
      #pragma unroll
      for (int j = 0; j < 8; ++j) {
        redf[wv * 256 + j * 16 + lane] = fsum[j];
        redf[wv * 256 + 128 + j * 16 + lane] = fsq[j];
      }
    }
    __syncthreads();
    float s = redf[tid] + redf[256 + tid] + redf[512 + tid] + redf[768 + tid];
    atomicAdd(&stats[tid], s);
  }
}

// =============================================================================
extern "C" void kernel_launch(void* const* d_in, const int* in_sizes, int n_in,
                              void* d_out, int out_size, void* d_ws, size_t ws_size,
                              hipStream_t stream) {
  const float* atom = (const float*)d_in[0];
  const float* nbr  = (const float*)d_in[1];
  const int*   esrc = (const int*)d_in[2];
  const int*   edst = (const int*)d_in[3];
  const float* W    = (const float*)d_in[4];
  const float* bvec = (const float*)d_in[5];
  const float* g1   = (const float*)d_in[6];
  const float* b1   = (const float*)d_in[7];
  const float* g2   = (const float*)d_in[8];
  const float* b2   = (const float*)d_in[9];
  float* out = (float*)d_out;
  char* ws = (char*)d_ws;

  float* stats1 = (float*)ws;          // [256]
  float* ab1    = stats1 + 256;        // [256]
  float* stats2 = stats1 + 512;        // [128]
  float* ab2    = stats1 + 640;        // [128]

  const size_t OFF_ATOM = 4096;
  const size_t SZ_ATOM  = (size_t)N_NODES * ATOMF * 2;    //   6.4 MB
  const size_t OFF_NBR  = OFF_ATOM + SZ_ATOM;             // msg overlays this
  const size_t SZ_NBR   = (size_t)N_EDGES * ATOMF * 2;    // 102.4 MB
  const size_t OFF_ZT   = OFF_NBR + SZ_NBR;
  const size_t SZ_ZT    = (size_t)N_EDGES * DOUT * 2;     // 204.8 MB
  const size_t NEED_OLD = OFF_ZT + SZ_ZT;                 // ~313.6 MB
  const size_t OFF_PERM = NEED_OLD;
  const size_t SZ_PERM  = (size_t)N_EDGES * 4;            //   3.2 MB
  const size_t OFF_DEG  = OFF_PERM + SZ_PERM;
  const size_t OFF_RP   = OFF_DEG + N_NODES * 4;
  const size_t OFF_CUR  = OFF_RP + (N_NODES + 1) * 4 + 12;   // keep 16B align
  const size_t NEED_NEW = OFF_CUR + N_NODES * 4;          // ~317.8 MB

  hipMemsetAsync(stats1, 0, 768 * sizeof(float), stream);

  if (ws_size >= NEED_NEW) {
    unsigned short* atom_bf = (unsigned short*)(ws + OFF_ATOM);
    unsigned short* nbr_bf  = (unsigned short*)(ws + OFF_NBR);
    unsigned short* zt      = (unsigned short*)(ws + OFF_ZT);
    unsigned short* msg     = nbr_bf;          // overlay: nbr_bf dead after GEMM
    int* iperm  = (int*)(ws + OFF_PERM);
    int* deg    = (int*)(ws + OFF_DEG);
    int* rowptr = (int*)(ws + OFF_RP);
    int* cursor = (int*)(ws + OFF_CUR);

    hipMemsetAsync(deg, 0, N_NODES * sizeof(int), stream);
    hist_k<<<(N_EDGES + 255) / 256, 256, 0, stream>>>(edst, deg);
    scan_k<<<1, 1024, 0, stream>>>(deg, rowptr, cursor);
    fill_k<<<(N_EDGES + 255) / 256, 256, 0, stream>>>(edst, cursor, iperm);

    precvt_k<<<2048, 256, 0, stream>>>(atom, nbr, atom_bf, nbr_bf);
    edge_gemm<<<768, 256, 0, stream>>>(atom_bf, nbr_bf, esrc, edst, W, stats1, zt);
    finalize1_k<<<1, 128, 0, stream>>>(stats1, g1, b1, ab1);

    msg_k<<<NTILES, 256, 0, stream>>>(zt, ab1, iperm, msg);
    gather_k<<<(N_NODES + 3) / 4, 256, 0, stream>>>(msg, rowptr, out);
  } else if (ws_size >= NEED_OLD) {
    unsigned short* atom_bf = (unsigned short*)(ws + OFF_ATOM);
    unsigned short* nbr_bf  = (unsigned short*)(ws + OFF_NBR);
    unsigned short* zt      = (unsigned short*)(ws + OFF_ZT);
    hipMemsetAsync(out, 0, (size_t)N_NODES * 64 * sizeof(float), stream);
    precvt_k<<<2048, 256, 0, stream>>>(atom, nbr, atom_bf, nbr_bf);
    edge_gemm<<<768, 256, 0, stream>>>(atom_bf, nbr_bf, esrc, edst, W, stats1, zt);
    finalize1_k<<<1, 128, 0, stream>>>(stats1, g1, b1, ab1);
    scatter_k<<<25000, 256, 0, stream>>>(zt, edst, ab1, out);
  } else {
    hipMemsetAsync(out, 0, (size_t)N_NODES * 64 * sizeof(float), stream);
    edge_pass<0><<<512, 256, 0, stream>>>(atom, nbr, esrc, edst, W, bvec,
                                          stats1, nullptr, nullptr);
    finalize1_k<<<1, 128, 0, stream>>>(stats1, g1, b1, ab1);
    edge_pass<1><<<512, 256, 0, stream>>>(atom, nbr, esrc, edst, W, bvec,
                                          nullptr, ab1, out);
  }

  stats2_k<<<512, 256, 0, stream>>>(out, stats2);
  finalize2_k<<<1, 64, 0, stream>>>(stats2, g2, b2, ab2);
  out_k<<<512, 256, 0, stream>>>(atom, ab2, out);
}

// Round 10
// 472.102 us; speedup vs baseline: 1.5921x; 1.1348x over previous
//
#include <hip/hip_runtime.h>
#include <hip/hip_fp16.h>
#include <math.h>

#define N_NODES 50000
#define N_EDGES 800000
#define ATOMF 64
#define DIN 192
#define DOUT 128
#define EPB 64
#define NTILES (N_EDGES / EPB)   // 12500
#define LDW 200                  // LDS row stride in bf16 (192 data + 8 pad = 25 x 16B chunks)
#define NSLOT (EPB * 25)         // 1600 16B-chunks per tile

typedef __attribute__((ext_vector_type(8))) short bf16x8;
typedef __attribute__((ext_vector_type(8))) short s16x8;
typedef __attribute__((ext_vector_type(4))) float f32x4;

__device__ __forceinline__ short f2bf(float f) {
  unsigned u = __float_as_uint(f);
  u += 0x7fffu + ((u >> 16) & 1u);   // RNE
  return (short)(u >> 16);
}
__device__ __forceinline__ float bf2f(unsigned short u) {
  return __uint_as_float(((unsigned)u) << 16);
}
__device__ __forceinline__ unsigned short f2h(float f) {
  __half h = __float2half_rn(f);     // v_cvt_f16_f32 (RNE)
  return *(unsigned short*)&h;
}
__device__ __forceinline__ float h2f(unsigned short u) {
  __half h = *(__half*)&u;
  return __half2float(h);            // v_cvt_f32_f16
}
__device__ __forceinline__ float softplus_f(float x) {
  return fmaxf(x, 0.f) + log1pf(__expf(-fabsf(x)));
}
__device__ __forceinline__ float sigmoid_f(float x) {
  return 1.f / (1.f + __expf(-x));
}
// fast variants for the 51.2M-element msg pass (err ~1e-6, threshold 0.24)
__device__ __forceinline__ float fast_sigmoid(float x) {
  return __builtin_amdgcn_rcpf(1.f + __expf(-x));
}
__device__ __forceinline__ float fast_softplus(float x) {
  return fmaxf(x, 0.f) + __logf(1.f + __expf(-fabsf(x)));
}

#define GLOAD16(g, l)                                                          \
  __builtin_amdgcn_global_load_lds(                                            \
      (const __attribute__((address_space(1))) void*)(g),                      \
      (__attribute__((address_space(3))) void*)(l), 16, 0, 0)

// ---------------- fp32 -> bf16 pre-convert + fused degree histogram ----------
__launch_bounds__(256)
__global__ void precvt_k(const float* __restrict__ atom,
                         const float* __restrict__ nbr,
                         const int* __restrict__ edst,
                         unsigned short* __restrict__ atom_bf,
                         unsigned short* __restrict__ nbr_bf,
                         int* __restrict__ deg) {
  const int NA = N_NODES * ATOMF / 8;        // 400000 chunks of 8
  const int NB = N_EDGES * ATOMF / 8;        // 6400000
  int gid = blockIdx.x * blockDim.x + threadIdx.x;
  int stride = gridDim.x * blockDim.x;
  if (deg) {   // fused histogram: 800k L2 atomics hide under the stream
    for (int i = gid; i < N_EDGES; i += stride) atomicAdd(&deg[edst[i]], 1);
  }
  for (int i = gid; i < NA + NB; i += stride) {
    const float* s;
    unsigned short* d;
    if (i < NA) { s = atom + (size_t)i * 8; d = atom_bf + (size_t)i * 8; }
    else        { s = nbr + (size_t)(i - NA) * 8; d = nbr_bf + (size_t)(i - NA) * 8; }
    float4 a = ((const float4*)s)[0];
    float4 b = ((const float4*)s)[1];
    s16x8 t;
    t[0] = f2bf(a.x); t[1] = f2bf(a.y); t[2] = f2bf(a.z); t[3] = f2bf(a.w);
    t[4] = f2bf(b.x); t[5] = f2bf(b.y); t[6] = f2bf(b.z); t[7] = f2bf(b.w);
    *(s16x8*)d = t;
  }
}

// ---------------- CSR build: scan (x4 vectorized) -> fill (inverse perm) -----
__launch_bounds__(1024)
__global__ void scan_k(const int* __restrict__ deg,
                       int* __restrict__ rowptr,
                       int* __restrict__ cursor) {
  __shared__ int wsum[16];
  const int tid = threadIdx.x;
  const int lane = tid & 63, wv = tid >> 6;
  const int N4 = N_NODES / 4;                // 12500 int4 chunks
  int base = 0;
  for (int c0 = 0; c0 < N4; c0 += 1024) {
    int i4 = c0 + tid;
    int4 v = make_int4(0, 0, 0, 0);
    if (i4 < N4) v = ((const int4*)deg)[i4];
    int t = v.x + v.y + v.z + v.w;
    int s = t;
    #pragma unroll
    for (int d = 1; d < 64; d <<= 1) {
      int u = __shfl_up(s, d, 64);
      if (lane >= d) s += u;
    }
    if (lane == 63) wsum[wv] = s;
    __syncthreads();
    if (wv == 0 && lane < 16) {
      int ws = wsum[lane];
      #pragma unroll
      for (int d = 1; d < 16; d <<= 1) {
        int u = __shfl_up(ws, d, 64);
        if (lane >= d) ws += u;
      }
      wsum[lane] = ws;
    }
    __syncthreads();
    int wbase = wv ? wsum[wv - 1] : 0;
    int excl = base + wbase + s - t;         // exclusive prefix for 4-chunk
    if (i4 < N4) {
      int4 r;
      r.x = excl;
      r.y = excl + v.x;
      r.z = r.y + v.y;
      r.w = r.z + v.z;
      ((int4*)rowptr)[i4] = r;
      ((int4*)cursor)[i4] = r;
    }
    int tot = wsum[15];
    __syncthreads();   // everyone done reading wsum before next iter overwrites
    base += tot;
  }
  if (tid == 0) rowptr[N_NODES] = base;      // == N_EDGES
}

__launch_bounds__(256)
__global__ void fill_k(const int* __restrict__ edst,
                       int* __restrict__ cursor,
                       int* __restrict__ iperm) {
  int gid = blockIdx.x * 256 + threadIdx.x;
  if (gid < N_EDGES) {
    int pos = atomicAdd(&cursor[edst[gid]], 1);
    iperm[gid] = pos;          // inverse perm: edge -> CSR slot
  }
}

// ---------------- single edge pass: gather -> MFMA -> z store + stats --------
// zt layout: zt[tile][col(128)][row(64)] fp16 (tile-transposed for wide stores)
// Round-6-verified m97 schedule: stage -> barrier -> MFMA+epilogue -> barrier.
// (Pipelined variants either raced (r2-4, r8) or lost occupancy (r9).)
__device__ __forceinline__ void stage_tile(const unsigned short* __restrict__ atom_bf,
                                           const unsigned short* __restrict__ nbr_bf,
                                           const int* __restrict__ esrc,
                                           const int* __restrict__ edst,
                                           int e0, unsigned short* lbase,
                                           const int* g_enc, int wv) {
  #pragma unroll
  for (int it = 0; it < 7; ++it) {
    if (it * 256 + wv * 64 < NSLOT) {        // wave-uniform tail guard
      int e = g_enc[it];
      int row = e & 255;
      int coff = (e >> 8) & 255;
      int sel = e >> 16;
      const unsigned short* src;
      if (sel < 2) {
        const int* ip = sel ? edst : esrc;
        int idx = ip[e0 + row];
        src = atom_bf + (size_t)idx * ATOMF + coff;
      } else {
        src = nbr_bf + (size_t)(e0 + row) * ATOMF + coff;
      }
      GLOAD16(src, lbase + (size_t)(it * 256 + wv * 64) * 8);
    }
  }
}

__launch_bounds__(256, 4)
__global__ void edge_gemm(const unsigned short* __restrict__ atom_bf,
                          const unsigned short* __restrict__ nbr_bf,
                          const int* __restrict__ esrc,
                          const int* __restrict__ edst,
                          const float* __restrict__ W,
                          float* __restrict__ stats,
                          unsigned short* __restrict__ zt) {
  __shared__ unsigned short Tl[EPB * LDW];   // 25600 B -> 6 blocks/CU by LDS

  const int tid = threadIdx.x;
  const int lane = tid & 63;
  const int wv = tid >> 6;
  const int l15 = lane & 15;
  const int lg = lane >> 4;
  const int colF = wv * 16 + l15;            // filter column
  const int colC = colF + 64;                // core column

  // W fragments in registers: wf[cg][kk][jj] = W[kk*32+lg*8+jj][cg*64+colF]
  bf16x8 wf[2][6];
  #pragma unroll
  for (int cg = 0; cg < 2; ++cg) {
    #pragma unroll
    for (int kk = 0; kk < 6; ++kk) {
      bf16x8 t;
      #pragma unroll
      for (int jj = 0; jj < 8; ++jj)
        t[jj] = f2bf(W[(size_t)(kk * 32 + lg * 8 + jj) * 128 + cg * 64 + colF]);
      wf[cg][kk] = t;
    }
  }

  // slot s = it*256+tid -> (row = s/25, w = s%25)
  // w<8: atom[src]; w<16: atom[dst]; w<24: nbr; w==24: pad (harmless load)
  int g_enc[7];
  #pragma unroll
  for (int it = 0; it < 7; ++it) {
    int s = it * 256 + tid;
    if (s >= NSLOT) s = 0;                   // dead slot (wave guard at use)
    int row = s / 25;
    int w = s - row * 25;
    int sel, coff;
    if (w < 8)       { sel = 0; coff = w * 8; }
    else if (w < 16) { sel = 1; coff = (w - 8) * 8; }
    else             { sel = 2; coff = (w < 24 ? (w - 16) * 8 : 0); }
    g_enc[it] = row | (coff << 8) | (sel << 16);
  }

  float fs[2] = {0.f, 0.f}, fq[2] = {0.f, 0.f};

  for (int tile = blockIdx.x; tile < NTILES; tile += gridDim.x) {
    stage_tile(atom_bf, nbr_bf, esrc, edst, tile * EPB, Tl, g_enc, wv);
    __syncthreads();   // vmcnt(0) drain: Tl fully staged before any read

    f32x4 acc[2][4] = {};
    #pragma unroll
    for (int rg = 0; rg < 4; ++rg) {
      #pragma unroll
      for (int kk = 0; kk < 6; ++kk) {
        bf16x8 a = *(const bf16x8*)&Tl[(rg * 16 + l15) * LDW + kk * 32 + lg * 8];
        acc[0][rg] = __builtin_amdgcn_mfma_f32_16x16x32_bf16(a, wf[0][kk], acc[0][rg], 0, 0, 0);
        acc[1][rg] = __builtin_amdgcn_mfma_f32_16x16x32_bf16(a, wf[1][kk], acc[1][rg], 0, 0, 0);
      }
    }

    // epilogue: stats + fp16 pack + 8B stores; D: row = rg*16 + lg*4 + r
    #pragma unroll
    for (int cg = 0; cg < 2; ++cg) {
      unsigned short* zb = zt + ((size_t)tile * 128 + cg * 64 + colF) * 64 + lg * 4;
      #pragma unroll
      for (int rg = 0; rg < 4; ++rg) {
        float z0 = acc[cg][rg][0], z1 = acc[cg][rg][1];
        float z2 = acc[cg][rg][2], z3 = acc[cg][rg][3];
        fs[cg] += (z0 + z1) + (z2 + z3);
        fq[cg] += z0 * z0 + z1 * z1 + z2 * z2 + z3 * z3;
        uint2 p;
        p.x = (unsigned)f2h(z0) | ((unsigned)f2h(z1) << 16);
        p.y = (unsigned)f2h(z2) | ((unsigned)f2h(z3) << 16);
        *(uint2*)(zb + rg * 16) = p;
      }
    }
    __syncthreads();   // all LDS reads done before next tile's stage overwrites
  }

  #pragma unroll
  for (int cg = 0; cg < 2; ++cg) {
    fs[cg] += __shfl_xor(fs[cg], 16, 64); fs[cg] += __shfl_xor(fs[cg], 32, 64);
    fq[cg] += __shfl_xor(fq[cg], 16, 64); fq[cg] += __shfl_xor(fq[cg], 32, 64);
  }
  if (lane < 16) {
    atomicAdd(&stats[colF], fs[0]);
    atomicAdd(&stats[colC], fs[1]);
    atomicAdd(&stats[128 + colF], fq[0]);
    atomicAdd(&stats[128 + colC], fq[1]);
  }
}

// ---------------- BN1 finalize (b_full == 0; bias cancels inside BN anyway) --
__global__ void finalize1_k(const float* __restrict__ stats,
                            const float* __restrict__ g,
                            const float* __restrict__ be,
                            float* __restrict__ ab) {
  int n = threadIdx.x;   // 128
  float mu = stats[n] * (1.f / N_EDGES);
  float var = stats[128 + n] * (1.f / N_EDGES) - mu * mu;
  float a = g[n] * rsqrtf(var + 1e-5f);
  ab[n] = a;
  ab[128 + n] = be[n] - mu * a;
}

// ---------------- gate -> msg in CSR order (via LDS transpose) ---------------
// one block per tile: read zt[tile] (col-major), write msg[iperm[e]][64]
__launch_bounds__(256)
__global__ void msg_k(const unsigned short* __restrict__ zt,
                      const float* __restrict__ ab,
                      const int* __restrict__ iperm,
                      unsigned short* __restrict__ msg) {
  __shared__ unsigned short ml[64][72];      // +8 pad
  const int tile = blockIdx.x;
  const int tid = threadIdx.x;
  const int c = tid & 63;                    // filter col (core = c+64)
  const int rg = tid >> 6;                   // rows rg*16 .. +15
  const unsigned short* fb = zt + ((size_t)tile * 128 + c) * 64 + rg * 16;
  const unsigned short* gb = fb + (size_t)64 * 64;
  s16x8 f0 = *(const s16x8*)fb;
  s16x8 f1 = *(const s16x8*)(fb + 8);
  s16x8 g0 = *(const s16x8*)gb;
  s16x8 g1 = *(const s16x8*)(gb + 8);
  float af = ab[c], cf = ab[128 + c];
  float ag = ab[64 + c], cg = ab[192 + c];
  #pragma unroll
  for (int k = 0; k < 16; ++k) {
    unsigned short fu = (unsigned short)(k < 8 ? f0[k] : f1[k - 8]);
    unsigned short gu = (unsigned short)(k < 8 ? g0[k] : g1[k - 8]);
    float f = af * h2f(fu) + cf;
    float g = ag * h2f(gu) + cg;
    ml[rg * 16 + k][c] = f2h(fast_sigmoid(f) * fast_softplus(g));
  }
  const int r = tid >> 2;
  const int pos = iperm[tile * 64 + r];      // CSR slot for this edge row
  __syncthreads();
  const int cq = (tid & 3) * 16;
  s16x8 o0, o1;
  #pragma unroll
  for (int k = 0; k < 8; ++k) { o0[k] = ml[r][cq + k]; o1[k] = ml[r][cq + 8 + k]; }
  unsigned short* ob = msg + (size_t)pos * 64 + cq;
  *(s16x8*)ob = o0;
  *(s16x8*)(ob + 8) = o1;
}

// ---------------- gather: one wave per node, 8 CSR rows per iteration --------
// lane = g*?: g = lane>>3 (edge subslot 0..7), q = lane&7 (16B chunk of row).
// Wave reads 1KB contiguous (8 rows x 128B) per iteration; 3-shuffle reduce.
__launch_bounds__(256)
__global__ void gather_k(const unsigned short* __restrict__ msg,
                         const int* __restrict__ rowptr,
                         float* __restrict__ out) {
  int n = blockIdx.x * 4 + (threadIdx.x >> 6);
  if (n >= N_NODES) return;
  int lane = threadIdx.x & 63;
  int g = lane >> 3;                         // row offset within 8-group
  int q = lane & 7;                          // 16B chunk: cols 8q..8q+7
  int s = rowptr[n], e = rowptr[n + 1];
  float acc[8] = {0.f, 0.f, 0.f, 0.f, 0.f, 0.f, 0.f, 0.f};
  for (int i = s + g; i < e; i += 8) {
    s16x8 v = *(const s16x8*)(msg + (size_t)i * 64 + q * 8);
    #pragma unroll
    for (int k = 0; k < 8; ++k) acc[k] += h2f((unsigned short)v[k]);
  }
  #pragma unroll
  for (int k = 0; k < 8; ++k) {              // reduce across g (bits 3..5)
    acc[k] += __shfl_xor(acc[k], 8, 64);
    acc[k] += __shfl_xor(acc[k], 16, 64);
    acc[k] += __shfl_xor(acc[k], 32, 64);
  }
  if (g == 0) {                              // lanes 0..7 write the 256B row
    float4 a = make_float4(acc[0], acc[1], acc[2], acc[3]);
    float4 b = make_float4(acc[4], acc[5], acc[6], acc[7]);
    float4* ob = (float4*)(out + (size_t)n * 64 + q * 8);
    ob[0] = a; ob[1] = b;
  }
}

// ---------------- node-side stats / finalize / output ------------------------
__launch_bounds__(256)
__global__ void stats2_k(const float* __restrict__ upd, float* __restrict__ stats2) {
  int tid = threadIdx.x;
  int gid = blockIdx.x * 256 + tid;
  int stride = gridDim.x * 256;
  float4 s = make_float4(0.f, 0.f, 0.f, 0.f);
  float4 q = make_float4(0.f, 0.f, 0.f, 0.f);
  for (int i = gid; i < N_NODES * 16; i += stride) {
    float4 v = ((const float4*)upd)[i];
    s.x += v.x; s.y += v.y; s.z += v.z; s.w += v.w;
    q.x += v.x * v.x; q.y += v.y * v.y; q.z += v.z * v.z; q.w += v.w * v.w;
  }
  int lane = tid & 63;
  int wv = tid >> 6;
  s.x += __shfl_xor(s.x, 16, 64); s.x += __shfl_xor(s.x, 32, 64);
  s.y += __shfl_xor(s.y, 16, 64); s.y += __shfl_xor(s.y, 32, 64);
  s.z += __shfl_xor(s.z, 16, 64); s.z += __shfl_xor(s.z, 32, 64);
  s.w += __shfl_xor(s.w, 16, 64); s.w += __shfl_xor(s.w, 32, 64);
  q.x += __shfl_xor(q.x, 16, 64); q.x += __shfl_xor(q.x, 32, 64);
  q.y += __shfl_xor(q.y, 16, 64); q.y += __shfl_xor(q.y, 32, 64);
  q.z += __shfl_xor(q.z, 16, 64); q.z += __shfl_xor(q.z, 32, 64);
  q.w += __shfl_xor(q.w, 16, 64); q.w += __shfl_xor(q.w, 32, 64);
  __shared__ float red[4 * 128];
  if (lane < 16) {
    int f = lane * 4;
    red[wv * 128 + f + 0] = s.x; red[wv * 128 + f + 1] = s.y;
    red[wv * 128 + f + 2] = s.z; red[wv * 128 + f + 3] = s.w;
    red[wv * 128 + 64 + f + 0] = q.x; red[wv * 128 + 64 + f + 1] = q.y;
    red[wv * 128 + 64 + f + 2] = q.z; red[wv * 128 + 64 + f + 3] = q.w;
  }
  __syncthreads();
  if (tid < 128) {
    float v = red[tid] + red[128 + tid] + red[256 + tid] + red[384 + tid];
    atomicAdd(&stats2[tid], v);
  }
}

__global__ void finalize2_k(const float* __restrict__ stats2,
                            const float* __restrict__ g,
                            const float* __restrict__ be,
                            float* __restrict__ ab2) {
  int f = threadIdx.x;   // 64
  float mu = stats2[f] * (1.f / N_NODES);
  float var = stats2[64 + f] * (1.f / N_NODES) - mu * mu;
  float a = g[f] * rsqrtf(var + 1e-5f);
  ab2[f] = a;
  ab2[64 + f] = be[f] - mu * a;
}

__launch_bounds__(256)
__global__ void out_k(const float* __restrict__ atom,
                      const float* __restrict__ ab2,
                      float* __restrict__ out) {
  int gid = blockIdx.x * 256 + threadIdx.x;
  int stride = gridDim.x * 256;
  for (int i = gid; i < N_NODES * 16; i += stride) {
    float4 u = ((const float4*)out)[i];
    float4 x = ((const float4*)atom)[i];
    int f = (i & 15) * 4;
    float4 r;
    r.x = softplus_f(x.x + u.x * ab2[f + 0] + ab2[64 + f + 0]);
    r.y = softplus_f(x.y + u.y * ab2[f + 1] + ab2[64 + f + 1]);
    r.z = softplus_f(x.z + u.z * ab2[f + 2] + ab2[64 + f + 2]);
    r.w = softplus_f(x.w + u.w * ab2[f + 3] + ab2[64 + f + 3]);
    ((float4*)out)[i] = r;
  }
}

// ---------------- scatter path (round-5 known-good, mid fallback) ------------
__launch_bounds__(256)
__global__ void scatter_k(const unsigned short* __restrict__ zt,
                          const int* __restrict__ edst,
                          const float* __restrict__ ab,
                          float* __restrict__ out) {
  int gid = blockIdx.x * 256 + threadIdx.x;  // (tile, c, r8)
  int r8 = gid & 7;
  int c = (gid >> 3) & 63;
  int tile = gid >> 9;
  const unsigned short* fb = zt + ((size_t)tile * 128 + c) * 64 + r8 * 8;
  const unsigned short* gb = fb + 64 * 64;
  s16x8 f8 = *(const s16x8*)fb;
  s16x8 g8 = *(const s16x8*)gb;
  float af = ab[c], cf = ab[128 + c];
  float ag = ab[64 + c], cg = ab[192 + c];
  int4 d0 = *(const int4*)(edst + tile * 64 + r8 * 8);
  int4 d1 = *(const int4*)(edst + tile * 64 + r8 * 8 + 4);
  int dsts[8] = {d0.x, d0.y, d0.z, d0.w, d1.x, d1.y, d1.z, d1.w};
  #pragma unroll
  for (int i = 0; i < 8; ++i) {
    float f = af * h2f((unsigned short)f8[i]) + cf;
    float g = ag * h2f((unsigned short)g8[i]) + cg;
    float m = sigmoid_f(f) * softplus_f(g);
    atomicAdd(out + (size_t)dsts[i] * ATOMF + c, m);
  }
}

// ================= FALLBACK (round-1 two-pass path, known-good) ==============
template<int PASS>
__launch_bounds__(256, 2)
__global__ void edge_pass(const float* __restrict__ atom,
                          const float* __restrict__ nbr,
                          const int* __restrict__ esrc,
                          const int* __restrict__ edst,
                          const float* __restrict__ W,
                          const float* __restrict__ bvec,
                          float* __restrict__ stats,
                          const float* __restrict__ ab,
                          float* __restrict__ upd) {
  __shared__ short Wl[DOUT * LDW];
  __shared__ short Tl[EPB * LDW];
  __shared__ int eix[2 * EPB];

  const int tid = threadIdx.x;
  const int lane = tid & 63;
  const int wv = tid >> 6;
  const int l15 = lane & 15;
  const int lg = lane >> 4;

  for (int i = tid; i < DIN * DOUT; i += 256) {
    int k = i >> 7, n = i & 127;
    Wl[n * LDW + k] = f2bf(W[i]);
  }
  float bcol[8], acol[8], ccol[8];
  #pragma unroll
  for (int j = 0; j < 8; ++j) {
    int n = j * 16 + l15;
    bcol[j] = bvec[n];
    if constexpr (PASS == 1) { acol[j] = ab[n]; ccol[j] = ab[DOUT + n]; }
    else { acol[j] = 0.f; ccol[j] = 0.f; }
  }
  float fsum[8], fsq[8];
  #pragma unroll
  for (int j = 0; j < 8; ++j) { fsum[j] = 0.f; fsq[j] = 0.f; }

  for (int tile = blockIdx.x; tile < NTILES; tile += gridDim.x) {
    const int e0 = tile * EPB;
    __syncthreads();
    if (tid < EPB) eix[tid] = esrc[e0 + tid];
    else if (tid < 2 * EPB) eix[tid] = edst[e0 + tid - EPB];
    __syncthreads();
    for (int i = tid; i < EPB * 96; i += 256) {
      int row = i / 96;
      int cl = (i - row * 96) * 2;
      const float* p;
      if (cl < 64)       p = atom + (size_t)eix[row] * 64 + cl;
      else if (cl < 128) p = atom + (size_t)eix[EPB + row] * 64 + (cl - 64);
      else               p = nbr + (size_t)(e0 + row) * 64 + (cl - 128);
      float2 v = *(const float2*)p;
      unsigned pk = (unsigned)(unsigned short)f2bf(v.x)
                  | ((unsigned)(unsigned short)f2bf(v.y) << 16);
      *(unsigned*)&Tl[row * LDW + cl] = pk;
    }
    __syncthreads();
    f32x4 acc[8] = {};
    const int abase = (wv * 16 + l15) * LDW + lg * 8;
    #pragma unroll
    for (int kk = 0; kk < 6; ++kk) {
      bf16x8 afr = *(const bf16x8*)&Tl[abase + kk * 32];
      #pragma unroll
      for (int j = 0; j < 8; ++j) {
        bf16x8 bfr = *(const bf16x8*)&Wl[(j * 16 + l15) * LDW + lg * 8 + kk * 32];
        acc[j] = __builtin_amdgcn_mfma_f32_16x16x32_bf16(afr, bfr, acc[j], 0, 0, 0);
      }
    }
    if constexpr (PASS == 0) {
      #pragma unroll
      for (int j = 0; j < 8; ++j)
        #pragma unroll
        for (int r = 0; r < 4; ++r) {
          float z = acc[j][r] + bcol[j];
          fsum[j] += z; fsq[j] += z * z;
        }
    } else {
      #pragma unroll
      for (int r = 0; r < 4; ++r) {
        int row = wv * 16 + lg * 4 + r;
        int d = eix[EPB + row];
        float* urow = upd + (size_t)d * 64;
        #pragma unroll
        for (int j = 0; j < 4; ++j) {
          float f = (acc[j][r] + bcol[j]) * acol[j] + ccol[j];
          float g = (acc[j + 4][r] + bcol[j + 4]) * acol[j + 4] + ccol[j + 4];
          atomicAdd(&urow[j * 16 + l15], sigmoid_f(f) * softplus_f(g));
        }
      }
    }
  }
  if constexpr (PASS == 0) {
    #pragma unroll
    for (int j = 0; j < 8; ++j) {
      fsum[j] += __shfl_xor(fsum[j], 16, 64);
      fsum[j] += __shfl_xor(fsum[j], 32, 64);
      fsq[j]  += __shfl_xor(fsq[j], 16, 64);
      fsq[j]  += __shfl_xor(fsq[j], 32, 64);
    }
    __syncthreads();
    float* redf = (float*)Tl;
    if (lane < 16) {
      #pragma unroll
      for (int j = 0; j < 8; ++j) {
        redf[wv * 256 + j * 16 + lane] = fsum[j];
        redf[wv * 256 + 128 + j * 16 + lane] = fsq[j];
      }
    }
    __syncthreads();
    float s = redf[tid] + redf[256 + tid] + redf[512 + tid] + redf[768 + tid];
    atomicAdd(&stats[tid], s);
  }
}

// =============================================================================
extern "C" void kernel_launch(void* const* d_in, const int* in_sizes, int n_in,
                              void* d_out, int out_size, void* d_ws, size_t ws_size,
                              hipStream_t stream) {
  const float* atom = (const float*)d_in[0];
  const float* nbr  = (const float*)d_in[1];
  const int*   esrc = (const int*)d_in[2];
  const int*   edst = (const int*)d_in[3];
  const float* W    = (const float*)d_in[4];
  const float* bvec = (const float*)d_in[5];
  const float* g1   = (const float*)d_in[6];
  const float* b1   = (const float*)d_in[7];
  const float* g2   = (const float*)d_in[8];
  const float* b2   = (const float*)d_in[9];
  float* out = (float*)d_out;
  char* ws = (char*)d_ws;

  float* stats1 = (float*)ws;          // [256]
  float* ab1    = stats1 + 256;        // [256]
  float* stats2 = stats1 + 512;        // [128]
  float* ab2    = stats1 + 640;        // [128]

  const size_t OFF_ATOM = 4096;
  const size_t SZ_ATOM  = (size_t)N_NODES * ATOMF * 2;    //   6.4 MB
  const size_t OFF_NBR  = OFF_ATOM + SZ_ATOM;             // msg overlays this
  const size_t SZ_NBR   = (size_t)N_EDGES * ATOMF * 2;    // 102.4 MB
  const size_t OFF_ZT   = OFF_NBR + SZ_NBR;
  const size_t SZ_ZT    = (size_t)N_EDGES * DOUT * 2;     // 204.8 MB
  const size_t NEED_OLD = OFF_ZT + SZ_ZT;                 // ~313.6 MB
  const size_t OFF_PERM = NEED_OLD;
  const size_t SZ_PERM  = (size_t)N_EDGES * 4;            //   3.2 MB
  const size_t OFF_DEG  = OFF_PERM + SZ_PERM;
  const size_t OFF_RP   = OFF_DEG + N_NODES * 4;
  const size_t OFF_CUR  = OFF_RP + (N_NODES + 1) * 4 + 12;   // keep 16B align
  const size_t NEED_NEW = OFF_CUR + N_NODES * 4;          // ~317.8 MB

  hipMemsetAsync(stats1, 0, 768 * sizeof(float), stream);

  if (ws_size >= NEED_NEW) {
    unsigned short* atom_bf = (unsigned short*)(ws + OFF_ATOM);
    unsigned short* nbr_bf  = (unsigned short*)(ws + OFF_NBR);
    unsigned short* zt      = (unsigned short*)(ws + OFF_ZT);
    unsigned short* msg     = nbr_bf;          // overlay: nbr_bf dead after GEMM
    int* iperm  = (int*)(ws + OFF_PERM);
    int* deg    = (int*)(ws + OFF_DEG);
    int* rowptr = (int*)(ws + OFF_RP);
    int* cursor = (int*)(ws + OFF_CUR);

    hipMemsetAsync(deg, 0, N_NODES * sizeof(int), stream);
    precvt_k<<<2048, 256, 0, stream>>>(atom, nbr, edst, atom_bf, nbr_bf, deg);
    scan_k<<<1, 1024, 0, stream>>>(deg, rowptr, cursor);
    fill_k<<<(N_EDGES + 255) / 256, 256, 0, stream>>>(edst, cursor, iperm);

    edge_gemm<<<1536, 256, 0, stream>>>(atom_bf, nbr_bf, esrc, edst, W, stats1, zt);
    finalize1_k<<<1, 128, 0, stream>>>(stats1, g1, b1, ab1);

    msg_k<<<NTILES, 256, 0, stream>>>(zt, ab1, iperm, msg);
    gather_k<<<(N_NODES + 3) / 4, 256, 0, stream>>>(msg, rowptr, out);
  } else if (ws_size >= NEED_OLD) {
    unsigned short* atom_bf = (unsigned short*)(ws + OFF_ATOM);
    unsigned short* nbr_bf  = (unsigned short*)(ws + OFF_NBR);
    unsigned short* zt      = (unsigned short*)(ws + OFF_ZT);
    hipMemsetAsync(out, 0, (size_t)N_NODES * 64 * sizeof(float), stream);
    precvt_k<<<2048, 256, 0, stream>>>(atom, nbr, edst, atom_bf, nbr_bf, nullptr);
    edge_gemm<<<1536, 256, 0, stream>>>(atom_bf, nbr_bf, esrc, edst, W, stats1, zt);
    finalize1_k<<<1, 128, 0, stream>>>(stats1, g1, b1, ab1);
    scatter_k<<<25000, 256, 0, stream>>>(zt, edst, ab1, out);
  } else {
    hipMemsetAsync(out, 0, (size_t)N_NODES * 64 * sizeof(float), stream);
    edge_pass<0><<<512, 256, 0, stream>>>(atom, nbr, esrc, edst, W, bvec,
                                          stats1, nullptr, nullptr);
    finalize1_k<<<1, 128, 0, stream>>>(stats1, g1, b1, ab1);
    edge_pass<1><<<512, 256, 0, stream>>>(atom, nbr, esrc, edst, W, bvec,
                                          nullptr, ab1, out);
  }

  stats2_k<<<512, 256, 0, stream>>>(out, stats2);
  finalize2_k<<<1, 64, 0, stream>>>(stats2, g2, b2, ab2);
  out_k<<<512, 256, 0, stream>>>(atom, ab2, out);
}

// Round 11
// 452.937 us; speedup vs baseline: 1.6594x; 1.0423x over previous
//
#include <hip/hip_runtime.h>
#include <hip/hip_fp16.h>
#include <math.h>

#define N_NODES 50000
#define N_EDGES 800000
#define ATOMF 64
#define DIN 192
#define DOUT 128
#define EPB 64
#define NTILES (N_EDGES / EPB)   // 12500
#define LDW 200                  // LDS row stride in bf16 (192 data + 8 pad = 25 x 16B chunks)
#define NSLOT (EPB * 25)         // 1600 16B-chunks per tile
#define ZLD 136                  // z-LDS row stride in fp16 (272B, 16B-aligned rows)

typedef __attribute__((ext_vector_type(8))) short bf16x8;
typedef __attribute__((ext_vector_type(8))) short s16x8;
typedef __attribute__((ext_vector_type(4))) float f32x4;

__device__ __forceinline__ short f2bf(float f) {
  unsigned u = __float_as_uint(f);
  u += 0x7fffu + ((u >> 16) & 1u);   // RNE
  return (short)(u >> 16);
}
__device__ __forceinline__ unsigned short f2h(float f) {
  __half h = __float2half_rn(f);     // v_cvt_f16_f32 (RNE)
  return *(unsigned short*)&h;
}
__device__ __forceinline__ float h2f(unsigned short u) {
  __half h = *(__half*)&u;
  return __half2float(h);            // v_cvt_f32_f16
}
__device__ __forceinline__ float softplus_f(float x) {
  return fmaxf(x, 0.f) + log1pf(__expf(-fabsf(x)));
}
__device__ __forceinline__ float sigmoid_f(float x) {
  return 1.f / (1.f + __expf(-x));
}
// fast variants for the 51.2M-element gate (err ~1e-6, threshold 0.24)
__device__ __forceinline__ float fast_sigmoid(float x) {
  return __builtin_amdgcn_rcpf(1.f + __expf(-x));
}
__device__ __forceinline__ float fast_softplus(float x) {
  return fmaxf(x, 0.f) + __logf(1.f + __expf(-fabsf(x)));
}

#define GLOAD16(g, l)                                                          \
  __builtin_amdgcn_global_load_lds(                                            \
      (const __attribute__((address_space(1))) void*)(g),                      \
      (__attribute__((address_space(3))) void*)(l), 16, 0, 0)

// ---------------- fp32 -> bf16 pre-convert + fused degree histogram ----------
__launch_bounds__(256)
__global__ void precvt_k(const float* __restrict__ atom,
                         const float* __restrict__ nbr,
                         const int* __restrict__ edst,
                         unsigned short* __restrict__ atom_bf,
                         unsigned short* __restrict__ nbr_bf,
                         int* __restrict__ deg) {
  const int NA = N_NODES * ATOMF / 8;        // 400000 chunks of 8
  const int NB = N_EDGES * ATOMF / 8;        // 6400000
  int gid = blockIdx.x * blockDim.x + threadIdx.x;
  int stride = gridDim.x * blockDim.x;
  if (deg) {   // fused histogram: 800k L2 atomics hide under the stream
    for (int i = gid; i < N_EDGES; i += stride) atomicAdd(&deg[edst[i]], 1);
  }
  for (int i = gid; i < NA + NB; i += stride) {
    const float* s;
    unsigned short* d;
    if (i < NA) { s = atom + (size_t)i * 8; d = atom_bf + (size_t)i * 8; }
    else        { s = nbr + (size_t)(i - NA) * 8; d = nbr_bf + (size_t)(i - NA) * 8; }
    float4 a = ((const float4*)s)[0];
    float4 b = ((const float4*)s)[1];
    s16x8 t;
    t[0] = f2bf(a.x); t[1] = f2bf(a.y); t[2] = f2bf(a.z); t[3] = f2bf(a.w);
    t[4] = f2bf(b.x); t[5] = f2bf(b.y); t[6] = f2bf(b.z); t[7] = f2bf(b.w);
    *(s16x8*)d = t;
  }
}

// ---------------- CSR build: scan (x4 vectorized) -> fill (inverse perm) -----
__launch_bounds__(1024)
__global__ void scan_k(const int* __restrict__ deg,
                       int* __restrict__ rowptr,
                       int* __restrict__ cursor) {
  __shared__ int wsum[16];
  const int tid = threadIdx.x;
  const int lane = tid & 63, wv = tid >> 6;
  const int N4 = N_NODES / 4;                // 12500 int4 chunks
  int base = 0;
  for (int c0 = 0; c0 < N4; c0 += 1024) {
    int i4 = c0 + tid;
    int4 v = make_int4(0, 0, 0, 0);
    if (i4 < N4) v = ((const int4*)deg)[i4];
    int t = v.x + v.y + v.z + v.w;
    int s = t;
    #pragma unroll
    for (int d = 1; d < 64; d <<= 1) {
      int u = __shfl_up(s, d, 64);
      if (lane >= d) s += u;
    }
    if (lane == 63) wsum[wv] = s;
    __syncthreads();
    if (wv == 0 && lane < 16) {
      int ws = wsum[lane];
      #pragma unroll
      for (int d = 1; d < 16; d <<= 1) {
        int u = __shfl_up(ws, d, 64);
        if (lane >= d) ws += u;
      }
      wsum[lane] = ws;
    }
    __syncthreads();
    int wbase = wv ? wsum[wv - 1] : 0;
    int excl = base + wbase + s - t;         // exclusive prefix for 4-chunk
    if (i4 < N4) {
      int4 r;
      r.x = excl;
      r.y = excl + v.x;
      r.z = r.y + v.y;
      r.w = r.z + v.z;
      ((int4*)rowptr)[i4] = r;
      ((int4*)cursor)[i4] = r;
    }
    int tot = wsum[15];
    __syncthreads();   // everyone done reading wsum before next iter overwrites
    base += tot;
  }
  if (tid == 0) rowptr[N_NODES] = base;      // == N_EDGES
}

__launch_bounds__(256)
__global__ void fill_k(const int* __restrict__ edst,
                       int* __restrict__ cursor,
                       int* __restrict__ iperm) {
  int gid = blockIdx.x * 256 + threadIdx.x;
  if (gid < N_EDGES) {
    int pos = atomicAdd(&cursor[edst[gid]], 1);
    iperm[gid] = pos;          // inverse perm: edge -> CSR slot
  }
}

// ---------------- edge pass: gather -> MFMA -> z rows at CSR slots + stats ---
// z_csr layout: zc[pos][128] fp16, row-major, pos = CSR slot of the edge.
// Barrier schedule per tile (proven-invariant class: every LDS producer/
// consumer pair separated by a barrier; stage-DMA overwrites Tl only after
// the barrier that post-dates all reads of it):
//   stage(Tl) ; [A] drain+bar ; MFMA reads Tl ; [B] bar ;
//   ds_write z->Tl ; [C] bar ; ds_read rows + global write ; [D] bar ; loop
__device__ __forceinline__ void stage_tile(const unsigned short* __restrict__ atom_bf,
                                           const unsigned short* __restrict__ nbr_bf,
                                           const int* __restrict__ esrc,
                                           const int* __restrict__ edst,
                                           int e0, unsigned short* lbase,
                                           const int* g_enc, int wv) {
  #pragma unroll
  for (int it = 0; it < 7; ++it) {
    if (it * 256 + wv * 64 < NSLOT) {        // wave-uniform tail guard
      int e = g_enc[it];
      int row = e & 255;
      int coff = (e >> 8) & 255;
      int sel = e >> 16;
      const unsigned short* src;
      if (sel < 2) {
        const int* ip = sel ? edst : esrc;
        int idx = ip[e0 + row];
        src = atom_bf + (size_t)idx * ATOMF + coff;
      } else {
        src = nbr_bf + (size_t)(e0 + row) * ATOMF + coff;
      }
      GLOAD16(src, lbase + (size_t)(it * 256 + wv * 64) * 8);
    }
  }
}

__launch_bounds__(256, 4)
__global__ void edge_gemm(const unsigned short* __restrict__ atom_bf,
                          const unsigned short* __restrict__ nbr_bf,
                          const int* __restrict__ esrc,
                          const int* __restrict__ edst,
                          const int* __restrict__ iperm,
                          const float* __restrict__ W,
                          float* __restrict__ stats,
                          unsigned short* __restrict__ zc) {
  __shared__ unsigned short Tl[EPB * LDW];   // 25600 B; reused as z-LDS (17 KB)

  const int tid = threadIdx.x;
  const int lane = tid & 63;
  const int wv = tid >> 6;
  const int l15 = lane & 15;
  const int lg = lane >> 4;
  const int colF = wv * 16 + l15;            // filter column
  const int colC = colF + 64;                // core column

  // W fragments in registers: wf[cg][kk][jj] = W[kk*32+lg*8+jj][cg*64+colF]
  bf16x8 wf[2][6];
  #pragma unroll
  for (int cg = 0; cg < 2; ++cg) {
    #pragma unroll
    for (int kk = 0; kk < 6; ++kk) {
      bf16x8 t;
      #pragma unroll
      for (int jj = 0; jj < 8; ++jj)
        t[jj] = f2bf(W[(size_t)(kk * 32 + lg * 8 + jj) * 128 + cg * 64 + colF]);
      wf[cg][kk] = t;
    }
  }

  // slot s = it*256+tid -> (row = s/25, w = s%25)
  // w<8: atom[src]; w<16: atom[dst]; w<24: nbr; w==24: pad (harmless load)
  int g_enc[7];
  #pragma unroll
  for (int it = 0; it < 7; ++it) {
    int s = it * 256 + tid;
    if (s >= NSLOT) s = 0;                   // dead slot (wave guard at use)
    int row = s / 25;
    int w = s - row * 25;
    int sel, coff;
    if (w < 8)       { sel = 0; coff = w * 8; }
    else if (w < 16) { sel = 1; coff = (w - 8) * 8; }
    else             { sel = 2; coff = (w < 24 ? (w - 16) * 8 : 0); }
    g_enc[it] = row | (coff << 8) | (sel << 16);
  }

  const int orow = tid >> 2;                 // output row 0..63
  const int oq = tid & 3;                    // 32-col chunk 0..3

  float fs[2] = {0.f, 0.f}, fq[2] = {0.f, 0.f};

  for (int tile = blockIdx.x; tile < NTILES; tile += gridDim.x) {
    stage_tile(atom_bf, nbr_bf, esrc, edst, tile * EPB, Tl, g_enc, wv);
    __syncthreads();   // [A] vmcnt(0) drain: Tl fully staged before any read

    f32x4 acc[2][4] = {};
    #pragma unroll
    for (int rg = 0; rg < 4; ++rg) {
      #pragma unroll
      for (int kk = 0; kk < 6; ++kk) {
        bf16x8 a = *(const bf16x8*)&Tl[(rg * 16 + l15) * LDW + kk * 32 + lg * 8];
        acc[0][rg] = __builtin_amdgcn_mfma_f32_16x16x32_bf16(a, wf[0][kk], acc[0][rg], 0, 0, 0);
        acc[1][rg] = __builtin_amdgcn_mfma_f32_16x16x32_bf16(a, wf[1][kk], acc[1][rg], 0, 0, 0);
      }
    }

    // stats from registers (D layout: row = rg*16 + lg*4 + r, col = cg*64+colF)
    #pragma unroll
    for (int cg = 0; cg < 2; ++cg) {
      #pragma unroll
      for (int rg = 0; rg < 4; ++rg) {
        float z0 = acc[cg][rg][0], z1 = acc[cg][rg][1];
        float z2 = acc[cg][rg][2], z3 = acc[cg][rg][3];
        fs[cg] += (z0 + z1) + (z2 + z3);
        fq[cg] += z0 * z0 + z1 * z1 + z2 * z2 + z3 * z3;
      }
    }

    __syncthreads();   // [B] all MFMA ds_reads of Tl complete; Tl reusable

    // transpose: acc -> Tl-as-zLDS rows [64][ZLD] fp16
    #pragma unroll
    for (int cg = 0; cg < 2; ++cg)
      #pragma unroll
      for (int rg = 0; rg < 4; ++rg)
        #pragma unroll
        for (int r = 0; r < 4; ++r)
          Tl[(rg * 16 + lg * 4 + r) * ZLD + cg * 64 + colF] = f2h(acc[cg][rg][r]);

    __syncthreads();   // [C] z rows complete in LDS

    // write row orow (4 threads x 64B = 256B) to its CSR slot
    {
      int pos = iperm[tile * 64 + orow];
      const s16x8* src = (const s16x8*)&Tl[orow * ZLD + oq * 32];
      s16x8 v0 = src[0], v1 = src[1], v2 = src[2], v3 = src[3];
      unsigned short* dst = zc + (size_t)pos * 128 + oq * 32;
      *(s16x8*)dst = v0;
      *(s16x8*)(dst + 8) = v1;
      *(s16x8*)(dst + 16) = v2;
      *(s16x8*)(dst + 24) = v3;
    }

    __syncthreads();   // [D] zLDS reads done before next tile's DMA overwrites
  }

  #pragma unroll
  for (int cg = 0; cg < 2; ++cg) {
    fs[cg] += __shfl_xor(fs[cg], 16, 64); fs[cg] += __shfl_xor(fs[cg], 32, 64);
    fq[cg] += __shfl_xor(fq[cg], 16, 64); fq[cg] += __shfl_xor(fq[cg], 32, 64);
  }
  if (lane < 16) {
    atomicAdd(&stats[colF], fs[0]);
    atomicAdd(&stats[colC], fs[1]);
    atomicAdd(&stats[128 + colF], fq[0]);
    atomicAdd(&stats[128 + colC], fq[1]);
  }
}

// ---------------- BN1 finalize (b_full == 0; bias cancels inside BN anyway) --
__global__ void finalize1_k(const float* __restrict__ stats,
                            const float* __restrict__ g,
                            const float* __restrict__ be,
                            float* __restrict__ ab) {
  int n = threadIdx.x;   // 128
  float mu = stats[n] * (1.f / N_EDGES);
  float var = stats[128 + n] * (1.f / N_EDGES) - mu * mu;
  float a = g[n] * rsqrtf(var + 1e-5f);
  ab[n] = a;
  ab[128 + n] = be[n] - mu * a;
}

// ---------------- gather + gate: one wave per node, contiguous CSR rows ------
// per in-edge the wave reads one 256B z row; lane c computes
// sigmoid(af*f+cf)*softplus(ag*g+cg) and accumulates in fp32.
__launch_bounds__(256)
__global__ void gather_k(const unsigned short* __restrict__ zc,
                         const int* __restrict__ rowptr,
                         const float* __restrict__ ab,
                         float* __restrict__ out) {
  int n = blockIdx.x * 4 + (threadIdx.x >> 6);
  if (n >= N_NODES) return;
  int c = threadIdx.x & 63;
  float af = ab[c], cf = ab[128 + c];
  float ag = ab[64 + c], cg2 = ab[192 + c];
  int s = rowptr[n], e = rowptr[n + 1];
  float acc = 0.f;
  for (int i = s; i < e; ++i) {
    const unsigned short* row = zc + (size_t)i * 128;
    float f = af * h2f(row[c]) + cf;
    float g = ag * h2f(row[64 + c]) + cg2;
    acc += fast_sigmoid(f) * fast_softplus(g);
  }
  out[(size_t)n * 64 + c] = acc;
}

// ---------------- node-side stats / finalize / output ------------------------
__launch_bounds__(256)
__global__ void stats2_k(const float* __restrict__ upd, float* __restrict__ stats2) {
  int tid = threadIdx.x;
  int gid = blockIdx.x * 256 + tid;
  int stride = gridDim.x * 256;
  float4 s = make_float4(0.f, 0.f, 0.f, 0.f);
  float4 q = make_float4(0.f, 0.f, 0.f, 0.f);
  for (int i = gid; i < N_NODES * 16; i += stride) {
    float4 v = ((const float4*)upd)[i];
    s.x += v.x; s.y += v.y; s.z += v.z; s.w += v.w;
    q.x += v.x * v.x; q.y += v.y * v.y; q.z += v.z * v.z; q.w += v.w * v.w;
  }
  int lane = tid & 63;
  int wv = tid >> 6;
  s.x += __shfl_xor(s.x, 16, 64); s.x += __shfl_xor(s.x, 32, 64);
  s.y += __shfl_xor(s.y, 16, 64); s.y += __shfl_xor(s.y, 32, 64);
  s.z += __shfl_xor(s.z, 16, 64); s.z += __shfl_xor(s.z, 32, 64);
  s.w += __shfl_xor(s.w, 16, 64); s.w += __shfl_xor(s.w, 32, 64);
  q.x += __shfl_xor(q.x, 16, 64); q.x += __shfl_xor(q.x, 32, 64);
  q.y += __shfl_xor(q.y, 16, 64); q.y += __shfl_xor(q.y, 32, 64);
  q.z += __shfl_xor(q.z, 16, 64); q.z += __shfl_xor(q.z, 32, 64);
  q.w += __shfl_xor(q.w, 16, 64); q.w += __shfl_xor(q.w, 32, 64);
  __shared__ float red[4 * 128];
  if (lane < 16) {
    int f = lane * 4;
    red[wv * 128 + f + 0] = s.x; red[wv * 128 + f + 1] = s.y;
    red[wv * 128 + f + 2] = s.z; red[wv * 128 + f + 3] = s.w;
    red[wv * 128 + 64 + f + 0] = q.x; red[wv * 128 + 64 + f + 1] = q.y;
    red[wv * 128 + 64 + f + 2] = q.z; red[wv * 128 + 64 + f + 3] = q.w;
  }
  __syncthreads();
  if (tid < 128) {
    float v = red[tid] + red[128 + tid] + red[256 + tid] + red[384 + tid];
    atomicAdd(&stats2[tid], v);
  }
}

__global__ void finalize2_k(const float* __restrict__ stats2,
                            const float* __restrict__ g,
                            const float* __restrict__ be,
                            float* __restrict__ ab2) {
  int f = threadIdx.x;   // 64
  float mu = stats2[f] * (1.f / N_NODES);
  float var = stats2[64 + f] * (1.f / N_NODES) - mu * mu;
  float a = g[f] * rsqrtf(var + 1e-5f);
  ab2[f] = a;
  ab2[64 + f] = be[f] - mu * a;
}

__launch_bounds__(256)
__global__ void out_k(const float* __restrict__ atom,
                      const float* __restrict__ ab2,
                      float* __restrict__ out) {
  int gid = blockIdx.x * 256 + threadIdx.x;
  int stride = gridDim.x * 256;
  for (int i = gid; i < N_NODES * 16; i += stride) {
    float4 u = ((const float4*)out)[i];
    float4 x = ((const float4*)atom)[i];
    int f = (i & 15) * 4;
    float4 r;
    r.x = softplus_f(x.x + u.x * ab2[f + 0] + ab2[64 + f + 0]);
    r.y = softplus_f(x.y + u.y * ab2[f + 1] + ab2[64 + f + 1]);
    r.z = softplus_f(x.z + u.z * ab2[f + 2] + ab2[64 + f + 2]);
    r.w = softplus_f(x.w + u.w * ab2[f + 3] + ab2[64 + f + 3]);
    ((float4*)out)[i] = r;
  }
}

// ================= FALLBACK (round-1 two-pass path, known-good) ==============
template<int PASS>
__launch_bounds__(256, 2)
__global__ void edge_pass(const float* __restrict__ atom,
                          const float* __restrict__ nbr,
                          const int* __restrict__ esrc,
                          const int* __restrict__ edst,
                          const float* __restrict__ W,
                          const float* __restrict__ bvec,
                          float* __restrict__ stats,
                          const float* __restrict__ ab,
                          float* __restrict__ upd) {
  __shared__ short Wl[DOUT * LDW];
  __shared__ short Tl[EPB * LDW];
  __shared__ int eix[2 * EPB];

  const int tid = threadIdx.x;
  const int lane = tid & 63;
  const int wv = tid >> 6;
  const int l15 = lane & 15;
  const int lg = lane >> 4;

  for (int i = tid; i < DIN * DOUT; i += 256) {
    int k = i >> 7, n = i & 127;
    Wl[n * LDW + k] = f2bf(W[i]);
  }
  float bcol[8], acol[8], ccol[8];
  #pragma unroll
  for (int j = 0; j < 8; ++j) {
    int n = j * 16 + l15;
    bcol[j] = bvec[n];
    if constexpr (PASS == 1) { acol[j] = ab[n]; ccol[j] = ab[DOUT + n]; }
    else { acol[j] = 0.f; ccol[j] = 0.f; }
  }
  float fsum[8], fsq[8];
  #pragma unroll
  for (int j = 0; j < 8; ++j) { fsum[j] = 0.f; fsq[j] = 0.f; }

  for (int tile = blockIdx.x; tile < NTILES; tile += gridDim.x) {
    const int e0 = tile * EPB;
    __syncthreads();
    if (tid < EPB) eix[tid] = esrc[e0 + tid];
    else if (tid < 2 * EPB) eix[tid] = edst[e0 + tid - EPB];
    __syncthreads();
    for (int i = tid; i < EPB * 96; i += 256) {
      int row = i / 96;
      int cl = (i - row * 96) * 2;
      const float* p;
      if (cl < 64)       p = atom + (size_t)eix[row] * 64 + cl;
      else if (cl < 128) p = atom + (size_t)eix[EPB + row] * 64 + (cl - 64);
      else               p = nbr + (size_t)(e0 + row) * 64 + (cl - 128);
      float2 v = *(const float2*)p;
      unsigned pk = (unsigned)(unsigned short)f2bf(v.x)
                  | ((unsigned)(unsigned short)f2bf(v.y) << 16);
      *(unsigned*)&Tl[row * LDW + cl] = pk;
    }
    __syncthreads();
    f32x4 acc[8] = {};
    const int abase = (wv * 16 + l15) * LDW + lg * 8;
    #pragma unroll
    for (int kk = 0; kk < 6; ++kk) {
      bf16x8 afr = *(const bf16x8*)&Tl[abase + kk * 32];
      #pragma unroll
      for (int j = 0; j < 8; ++j) {
        bf16x8 bfr = *(const bf16x8*)&Wl[(j * 16 + l15) * LDW + lg * 8 + kk * 32];
        acc[j] = __builtin_amdgcn_mfma_f32_16x16x32_bf16(afr, bfr, acc[j], 0, 0, 0);
      }
    }
    if constexpr (PASS == 0) {
      #pragma unroll
      for (int j = 0; j < 8; ++j)
        #pragma unroll
        for (int r = 0; r < 4; ++r) {
          float z = acc[j][r] + bcol[j];
          fsum[j] += z; fsq[j] += z * z;
        }
    } else {
      #pragma unroll
      for (int r = 0; r < 4; ++r) {
        int row = wv * 16 + lg * 4 + r;
        int d = eix[EPB + row];
        float* urow = upd + (size_t)d * 64;
        #pragma unroll
        for (int j = 0; j < 4; ++j) {
          float f = (acc[j][r] + bcol[j]) * acol[j] + ccol[j];
          float g = (acc[j + 4][r] + bcol[j + 4]) * acol[j + 4] + ccol[j + 4];
          atomicAdd(&urow[j * 16 + l15], sigmoid_f(f) * softplus_f(g));
        }
      }
    }
  }
  if constexpr (PASS == 0) {
    #pragma unroll
    for (int j = 0; j < 8; ++j) {
      fsum[j] += __shfl_xor(fsum[j], 16, 64);
      fsum[j] += __shfl_xor(fsum[j], 32, 64);
      fsq[j]  += __shfl_xor(fsq[j], 16, 64);
      fsq[j]  += __shfl_xor(fsq[j], 32, 64);
    }
    __syncthreads();
    float* redf = (float*)Tl;
    if (lane < 16) {
      #pragma unroll
      for (int j = 0; j < 8; ++j) {
        redf[wv * 256 + j * 16 + lane] = fsum[j];
        redf[wv * 256 + 128 + j * 16 + lane] = fsq[j];
      }
    }
    __syncthreads();
    float s = redf[tid] + redf[256 + tid] + redf[512 + tid] + redf[768 + tid];
    atomicAdd(&stats[tid], s);
  }
}

// =============================================================================
extern "C" void kernel_launch(void* const* d_in, const int* in_sizes, int n_in,
                              void* d_out, int out_size, void* d_ws, size_t ws_size,
                              hipStream_t stream) {
  const float* atom = (const float*)d_in[0];
  const float* nbr  = (const float*)d_in[1];
  const int*   esrc = (const int*)d_in[2];
  const int*   edst = (const int*)d_in[3];
  const float* W    = (const float*)d_in[4];
  const float* bvec = (const float*)d_in[5];
  const float* g1   = (const float*)d_in[6];
  const float* b1   = (const float*)d_in[7];
  const float* g2   = (const float*)d_in[8];
  const float* b2   = (const float*)d_in[9];
  float* out = (float*)d_out;
  char* ws = (char*)d_ws;

  float* stats1 = (float*)ws;          // [256]
  float* ab1    = stats1 + 256;        // [256]
  float* stats2 = stats1 + 512;        // [128]
  float* ab2    = stats1 + 640;        // [128]

  const size_t OFF_ATOM = 4096;
  const size_t SZ_ATOM  = (size_t)N_NODES * ATOMF * 2;    //   6.4 MB
  const size_t OFF_NBR  = OFF_ATOM + SZ_ATOM;
  const size_t SZ_NBR   = (size_t)N_EDGES * ATOMF * 2;    // 102.4 MB
  const size_t OFF_ZT   = OFF_NBR + SZ_NBR;
  const size_t SZ_ZT    = (size_t)N_EDGES * DOUT * 2;     // 204.8 MB (z_csr)
  const size_t OFF_PERM = OFF_ZT + SZ_ZT;
  const size_t SZ_PERM  = (size_t)N_EDGES * 4;            //   3.2 MB
  const size_t OFF_DEG  = OFF_PERM + SZ_PERM;
  const size_t OFF_RP   = OFF_DEG + N_NODES * 4;
  const size_t OFF_CUR  = OFF_RP + (N_NODES + 1) * 4 + 12;   // keep 16B align
  const size_t NEED_NEW = OFF_CUR + N_NODES * 4;          // ~317.8 MB

  hipMemsetAsync(stats1, 0, 768 * sizeof(float), stream);

  if (ws_size >= NEED_NEW) {
    unsigned short* atom_bf = (unsigned short*)(ws + OFF_ATOM);
    unsigned short* nbr_bf  = (unsigned short*)(ws + OFF_NBR);
    unsigned short* zc      = (unsigned short*)(ws + OFF_ZT);
    int* iperm  = (int*)(ws + OFF_PERM);
    int* deg    = (int*)(ws + OFF_DEG);
    int* rowptr = (int*)(ws + OFF_RP);
    int* cursor = (int*)(ws + OFF_CUR);

    hipMemsetAsync(deg, 0, N_NODES * sizeof(int), stream);
    precvt_k<<<2048, 256, 0, stream>>>(atom, nbr, edst, atom_bf, nbr_bf, deg);
    scan_k<<<1, 1024, 0, stream>>>(deg, rowptr, cursor);
    fill_k<<<(N_EDGES + 255) / 256, 256, 0, stream>>>(edst, cursor, iperm);

    edge_gemm<<<1024, 256, 0, stream>>>(atom_bf, nbr_bf, esrc, edst, iperm,
                                        W, stats1, zc);
    finalize1_k<<<1, 128, 0, stream>>>(stats1, g1, b1, ab1);

    gather_k<<<(N_NODES + 3) / 4, 256, 0, stream>>>(zc, rowptr, ab1, out);
  } else {
    hipMemsetAsync(out, 0, (size_t)N_NODES * 64 * sizeof(float), stream);
    edge_pass<0><<<512, 256, 0, stream>>>(atom, nbr, esrc, edst, W, bvec,
                                          stats1, nullptr, nullptr);
    finalize1_k<<<1, 128, 0, stream>>>(stats1, g1, b1, ab1);
    edge_pass<1><<<512, 256, 0, stream>>>(atom, nbr, esrc, edst, W, bvec,
                                          nullptr, ab1, out);
  }

  stats2_k<<<512, 256, 0, stream>>>(out, stats2);
  finalize2_k<<<1, 64, 0, stream>>>(stats2, g2, b2, ab2);
  out_k<<<512, 256, 0, stream>>>(atom, ab2, out);
}

// Round 12
// 443.920 us; speedup vs baseline: 1.6931x; 1.0203x over previous
//
#include <hip/hip_runtime.h>
#include <hip/hip_fp16.h>
#include <math.h>

#define N_NODES 50000
#define N_EDGES 800000
#define ATOMF 64
#define DIN 192
#define DOUT 128
#define EPB 64
#define NTILES (N_EDGES / EPB)   // 12500
#define LDW 200                  // fallback LDS stride
#define ZLD 136                  // z-LDS row stride in fp16 (272B, 16B-aligned rows)

typedef __attribute__((ext_vector_type(8))) short bf16x8;
typedef __attribute__((ext_vector_type(8))) short s16x8;
typedef __attribute__((ext_vector_type(4))) float f32x4;

__device__ __forceinline__ short f2bf(float f) {
  unsigned u = __float_as_uint(f);
  u += 0x7fffu + ((u >> 16) & 1u);   // RNE
  return (short)(u >> 16);
}
__device__ __forceinline__ unsigned short f2h(float f) {
  __half h = __float2half_rn(f);     // v_cvt_f16_f32 (RNE)
  return *(unsigned short*)&h;
}
__device__ __forceinline__ float h2f(unsigned short u) {
  __half h = *(__half*)&u;
  return __half2float(h);            // v_cvt_f32_f16
}
__device__ __forceinline__ float softplus_f(float x) {
  return fmaxf(x, 0.f) + log1pf(__expf(-fabsf(x)));
}
__device__ __forceinline__ float sigmoid_f(float x) {
  return 1.f / (1.f + __expf(-x));
}
// fast variants for the 51.2M-element gate (err ~1e-6, threshold 0.24)
__device__ __forceinline__ float fast_sigmoid(float x) {
  return __builtin_amdgcn_rcpf(1.f + __expf(-x));
}
__device__ __forceinline__ float fast_softplus(float x) {
  return fmaxf(x, 0.f) + __logf(1.f + __expf(-fabsf(x)));
}

// ---------------- fp32 -> bf16 pre-convert + fused degree histogram ----------
__launch_bounds__(256)
__global__ void precvt_k(const float* __restrict__ atom,
                         const float* __restrict__ nbr,
                         const int* __restrict__ edst,
                         unsigned short* __restrict__ atom_bf,
                         unsigned short* __restrict__ nbr_bf,
                         int* __restrict__ deg) {
  const int NA = N_NODES * ATOMF / 8;        // 400000 chunks of 8
  const int NB = N_EDGES * ATOMF / 8;        // 6400000
  int gid = blockIdx.x * blockDim.x + threadIdx.x;
  int stride = gridDim.x * blockDim.x;
  if (deg) {   // fused histogram: 800k L2 atomics hide under the stream
    for (int i = gid; i < N_EDGES; i += stride) atomicAdd(&deg[edst[i]], 1);
  }
  for (int i = gid; i < NA + NB; i += stride) {
    const float* s;
    unsigned short* d;
    if (i < NA) { s = atom + (size_t)i * 8; d = atom_bf + (size_t)i * 8; }
    else        { s = nbr + (size_t)(i - NA) * 8; d = nbr_bf + (size_t)(i - NA) * 8; }
    float4 a = ((const float4*)s)[0];
    float4 b = ((const float4*)s)[1];
    s16x8 t;
    t[0] = f2bf(a.x); t[1] = f2bf(a.y); t[2] = f2bf(a.z); t[3] = f2bf(a.w);
    t[4] = f2bf(b.x); t[5] = f2bf(b.y); t[6] = f2bf(b.z); t[7] = f2bf(b.w);
    *(s16x8*)d = t;
  }
}

// ---------------- CSR build: scan (x4 vectorized) -> fill (inverse perm) -----
__launch_bounds__(1024)
__global__ void scan_k(const int* __restrict__ deg,
                       int* __restrict__ rowptr,
                       int* __restrict__ cursor) {
  __shared__ int wsum[16];
  const int tid = threadIdx.x;
  const int lane = tid & 63, wv = tid >> 6;
  const int N4 = N_NODES / 4;                // 12500 int4 chunks
  int base = 0;
  for (int c0 = 0; c0 < N4; c0 += 1024) {
    int i4 = c0 + tid;
    int4 v = make_int4(0, 0, 0, 0);
    if (i4 < N4) v = ((const int4*)deg)[i4];
    int t = v.x + v.y + v.z + v.w;
    int s = t;
    #pragma unroll
    for (int d = 1; d < 64; d <<= 1) {
      int u = __shfl_up(s, d, 64);
      if (lane >= d) s += u;
    }
    if (lane == 63) wsum[wv] = s;
    __syncthreads();
    if (wv == 0 && lane < 16) {
      int ws = wsum[lane];
      #pragma unroll
      for (int d = 1; d < 16; d <<= 1) {
        int u = __shfl_up(ws, d, 64);
        if (lane >= d) ws += u;
      }
      wsum[lane] = ws;
    }
    __syncthreads();
    int wbase = wv ? wsum[wv - 1] : 0;
    int excl = base + wbase + s - t;         // exclusive prefix for 4-chunk
    if (i4 < N4) {
      int4 r;
      r.x = excl;
      r.y = excl + v.x;
      r.z = r.y + v.y;
      r.w = r.z + v.z;
      ((int4*)rowptr)[i4] = r;
      ((int4*)cursor)[i4] = r;
    }
    int tot = wsum[15];
    __syncthreads();   // everyone done reading wsum before next iter overwrites
    base += tot;
  }
  if (tid == 0) rowptr[N_NODES] = base;      // == N_EDGES
}

__launch_bounds__(256)
__global__ void fill_k(const int* __restrict__ edst,
                       int* __restrict__ cursor,
                       int* __restrict__ iperm) {
  int gid = blockIdx.x * 256 + threadIdx.x;
  if (gid < N_EDGES) {
    int pos = atomicAdd(&cursor[edst[gid]], 1);
    iperm[gid] = pos;          // inverse perm: edge -> CSR slot
  }
}

// ---------------- edge pass: DIRECT-LOAD fragments -> MFMA -> z rows ---------
// No LDS staging, no global_load_lds: each lane loads its 16B MFMA A-fragment
// straight from global (fragment cols kk*32+lg*8 never cross a 64-col source
// boundary; source select = kk>>1). Register-dest loads => normal compiler
// waitcnt/scheduling; the DMA-race class is gone by construction. LDS is used
// only for the z transpose (2 barriers/tile).
// z_csr layout: zc[pos][128] fp16, row-major, pos = CSR slot of the edge.
__launch_bounds__(256, 4)
__global__ void edge_gemm(const unsigned short* __restrict__ atom_bf,
                          const unsigned short* __restrict__ nbr_bf,
                          const int* __restrict__ esrc,
                          const int* __restrict__ edst,
                          const int* __restrict__ iperm,
                          const float* __restrict__ W,
                          float* __restrict__ stats,
                          unsigned short* __restrict__ zc) {
  __shared__ unsigned short Zl[EPB * ZLD];   // 17408 B (z transpose only)

  const int tid = threadIdx.x;
  const int lane = tid & 63;
  const int wv = tid >> 6;
  const int l15 = lane & 15;
  const int lg = lane >> 4;
  const int colF = wv * 16 + l15;            // filter column
  const int colC = colF + 64;                // core column

  // W fragments in registers: wf[cg][kk][jj] = W[kk*32+lg*8+jj][cg*64+colF]
  bf16x8 wf[2][6];
  #pragma unroll
  for (int cg = 0; cg < 2; ++cg) {
    #pragma unroll
    for (int kk = 0; kk < 6; ++kk) {
      bf16x8 t;
      #pragma unroll
      for (int jj = 0; jj < 8; ++jj)
        t[jj] = f2bf(W[(size_t)(kk * 32 + lg * 8 + jj) * 128 + cg * 64 + colF]);
      wf[cg][kk] = t;
    }
  }

  const int orow = tid >> 2;                 // output row 0..63
  const int oq = tid & 3;                    // 32-col chunk 0..3

  float fs[2] = {0.f, 0.f}, fq[2] = {0.f, 0.f};

  for (int tile = blockIdx.x; tile < NTILES; tile += gridDim.x) {
    const int e0 = tile * EPB;

    f32x4 acc[2][4] = {};
    #pragma unroll
    for (int rg = 0; rg < 4; ++rg) {
      int e = e0 + rg * 16 + l15;            // this lane's edge row
      const unsigned short* srcb = atom_bf + (size_t)esrc[e] * ATOMF + lg * 8;
      const unsigned short* dstb = atom_bf + (size_t)edst[e] * ATOMF + lg * 8;
      const unsigned short* nbrb = nbr_bf + (size_t)e * ATOMF + lg * 8;
      bf16x8 a0 = *(const bf16x8*)srcb;        // cols   0.. 31 slice
      bf16x8 a1 = *(const bf16x8*)(srcb + 32); // cols  32.. 63
      bf16x8 a2 = *(const bf16x8*)dstb;        // cols  64.. 95
      bf16x8 a3 = *(const bf16x8*)(dstb + 32); // cols  96..127
      bf16x8 a4 = *(const bf16x8*)nbrb;        // cols 128..159
      bf16x8 a5 = *(const bf16x8*)(nbrb + 32); // cols 160..191
      acc[0][rg] = __builtin_amdgcn_mfma_f32_16x16x32_bf16(a0, wf[0][0], acc[0][rg], 0, 0, 0);
      acc[1][rg] = __builtin_amdgcn_mfma_f32_16x16x32_bf16(a0, wf[1][0], acc[1][rg], 0, 0, 0);
      acc[0][rg] = __builtin_amdgcn_mfma_f32_16x16x32_bf16(a1, wf[0][1], acc[0][rg], 0, 0, 0);
      acc[1][rg] = __builtin_amdgcn_mfma_f32_16x16x32_bf16(a1, wf[1][1], acc[1][rg], 0, 0, 0);
      acc[0][rg] = __builtin_amdgcn_mfma_f32_16x16x32_bf16(a2, wf[0][2], acc[0][rg], 0, 0, 0);
      acc[1][rg] = __builtin_amdgcn_mfma_f32_16x16x32_bf16(a2, wf[1][2], acc[1][rg], 0, 0, 0);
      acc[0][rg] = __builtin_amdgcn_mfma_f32_16x16x32_bf16(a3, wf[0][3], acc[0][rg], 0, 0, 0);
      acc[1][rg] = __builtin_amdgcn_mfma_f32_16x16x32_bf16(a3, wf[1][3], acc[1][rg], 0, 0, 0);
      acc[0][rg] = __builtin_amdgcn_mfma_f32_16x16x32_bf16(a4, wf[0][4], acc[0][rg], 0, 0, 0);
      acc[1][rg] = __builtin_amdgcn_mfma_f32_16x16x32_bf16(a4, wf[1][4], acc[1][rg], 0, 0, 0);
      acc[0][rg] = __builtin_amdgcn_mfma_f32_16x16x32_bf16(a5, wf[0][5], acc[0][rg], 0, 0, 0);
      acc[1][rg] = __builtin_amdgcn_mfma_f32_16x16x32_bf16(a5, wf[1][5], acc[1][rg], 0, 0, 0);
    }

    // stats from registers (D layout: row = rg*16 + lg*4 + r, col = cg*64+colF)
    #pragma unroll
    for (int cg = 0; cg < 2; ++cg) {
      #pragma unroll
      for (int rg = 0; rg < 4; ++rg) {
        float z0 = acc[cg][rg][0], z1 = acc[cg][rg][1];
        float z2 = acc[cg][rg][2], z3 = acc[cg][rg][3];
        fs[cg] += (z0 + z1) + (z2 + z3);
        fq[cg] += z0 * z0 + z1 * z1 + z2 * z2 + z3 * z3;
      }
    }

    __syncthreads();   // [P] prior iteration's Zl row-reads complete

    // transpose: acc -> Zl rows [64][ZLD] fp16
    #pragma unroll
    for (int cg = 0; cg < 2; ++cg)
      #pragma unroll
      for (int rg = 0; rg < 4; ++rg)
        #pragma unroll
        for (int r = 0; r < 4; ++r)
          Zl[(rg * 16 + lg * 4 + r) * ZLD + cg * 64 + colF] = f2h(acc[cg][rg][r]);

    __syncthreads();   // [Q] z rows complete in LDS

    // write row orow (4 threads x 64B = 256B) to its CSR slot
    {
      int pos = iperm[tile * 64 + orow];
      const s16x8* src = (const s16x8*)&Zl[orow * ZLD + oq * 32];
      s16x8 v0 = src[0], v1 = src[1], v2 = src[2], v3 = src[3];
      unsigned short* dst = zc + (size_t)pos * 128 + oq * 32;
      *(s16x8*)dst = v0;
      *(s16x8*)(dst + 8) = v1;
      *(s16x8*)(dst + 16) = v2;
      *(s16x8*)(dst + 24) = v3;
    }
  }

  #pragma unroll
  for (int cg = 0; cg < 2; ++cg) {
    fs[cg] += __shfl_xor(fs[cg], 16, 64); fs[cg] += __shfl_xor(fs[cg], 32, 64);
    fq[cg] += __shfl_xor(fq[cg], 16, 64); fq[cg] += __shfl_xor(fq[cg], 32, 64);
  }
  if (lane < 16) {
    atomicAdd(&stats[colF], fs[0]);
    atomicAdd(&stats[colC], fs[1]);
    atomicAdd(&stats[128 + colF], fq[0]);
    atomicAdd(&stats[128 + colC], fq[1]);
  }
}

// ---------------- BN1 finalize (b_full == 0; bias cancels inside BN anyway) --
__global__ void finalize1_k(const float* __restrict__ stats,
                            const float* __restrict__ g,
                            const float* __restrict__ be,
                            float* __restrict__ ab) {
  int n = threadIdx.x;   // 128
  float mu = stats[n] * (1.f / N_EDGES);
  float var = stats[128 + n] * (1.f / N_EDGES) - mu * mu;
  float a = g[n] * rsqrtf(var + 1e-5f);
  ab[n] = a;
  ab[128 + n] = be[n] - mu * a;
}

// ---------------- gather + gate: one wave per node, contiguous CSR rows ------
__launch_bounds__(256)
__global__ void gather_k(const unsigned short* __restrict__ zc,
                         const int* __restrict__ rowptr,
                         const float* __restrict__ ab,
                         float* __restrict__ out) {
  int n = blockIdx.x * 4 + (threadIdx.x >> 6);
  if (n >= N_NODES) return;
  int c = threadIdx.x & 63;
  float af = ab[c], cf = ab[128 + c];
  float ag = ab[64 + c], cg2 = ab[192 + c];
  int s = rowptr[n], e = rowptr[n + 1];
  float acc = 0.f;
  int i = s;
  for (; i + 2 <= e; i += 2) {               // 2 rows/iter for MLP
    const unsigned short* r0 = zc + (size_t)i * 128;
    const unsigned short* r1 = r0 + 128;
    float f0 = af * h2f(r0[c]) + cf;
    float g0 = ag * h2f(r0[64 + c]) + cg2;
    float f1 = af * h2f(r1[c]) + cf;
    float g1 = ag * h2f(r1[64 + c]) + cg2;
    acc += fast_sigmoid(f0) * fast_softplus(g0);
    acc += fast_sigmoid(f1) * fast_softplus(g1);
  }
  if (i < e) {
    const unsigned short* r0 = zc + (size_t)i * 128;
    float f0 = af * h2f(r0[c]) + cf;
    float g0 = ag * h2f(r0[64 + c]) + cg2;
    acc += fast_sigmoid(f0) * fast_softplus(g0);
  }
  out[(size_t)n * 64 + c] = acc;
}

// ---------------- node-side stats / finalize / output ------------------------
__launch_bounds__(256)
__global__ void stats2_k(const float* __restrict__ upd, float* __restrict__ stats2) {
  int tid = threadIdx.x;
  int gid = blockIdx.x * 256 + tid;
  int stride = gridDim.x * 256;
  float4 s = make_float4(0.f, 0.f, 0.f, 0.f);
  float4 q = make_float4(0.f, 0.f, 0.f, 0.f);
  for (int i = gid; i < N_NODES * 16; i += stride) {
    float4 v = ((const float4*)upd)[i];
    s.x += v.x; s.y += v.y; s.z += v.z; s.w += v.w;
    q.x += v.x * v.x; q.y += v.y * v.y; q.z += v.z * v.z; q.w += v.w * v.w;
  }
  int lane = tid & 63;
  int wv = tid >> 6;
  s.x += __shfl_xor(s.x, 16, 64); s.x += __shfl_xor(s.x, 32, 64);
  s.y += __shfl_xor(s.y, 16, 64); s.y += __shfl_xor(s.y, 32, 64);
  s.z += __shfl_xor(s.z, 16, 64); s.z += __shfl_xor(s.z, 32, 64);
  s.w += __shfl_xor(s.w, 16, 64); s.w += __shfl_xor(s.w, 32, 64);
  q.x += __shfl_xor(q.x, 16, 64); q.x += __shfl_xor(q.x, 32, 64);
  q.y += __shfl_xor(q.y, 16, 64); q.y += __shfl_xor(q.y, 32, 64);
  q.z += __shfl_xor(q.z, 16, 64); q.z += __shfl_xor(q.z, 32, 64);
  q.w += __shfl_xor(q.w, 16, 64); q.w += __shfl_xor(q.w, 32, 64);
  __shared__ float red[4 * 128];
  if (lane < 16) {
    int f = lane * 4;
    red[wv * 128 + f + 0] = s.x; red[wv * 128 + f + 1] = s.y;
    red[wv * 128 + f + 2] = s.z; red[wv * 128 + f + 3] = s.w;
    red[wv * 128 + 64 + f + 0] = q.x; red[wv * 128 + 64 + f + 1] = q.y;
    red[wv * 128 + 64 + f + 2] = q.z; red[wv * 128 + 64 + f + 3] = q.w;
  }
  __syncthreads();
  if (tid < 128) {
    float v = red[tid] + red[128 + tid] + red[256 + tid] + red[384 + tid];
    atomicAdd(&stats2[tid], v);
  }
}

__global__ void finalize2_k(const float* __restrict__ stats2,
                            const float* __restrict__ g,
                            const float* __restrict__ be,
                            float* __restrict__ ab2) {
  int f = threadIdx.x;   // 64
  float mu = stats2[f] * (1.f / N_NODES);
  float var = stats2[64 + f] * (1.f / N_NODES) - mu * mu;
  float a = g[f] * rsqrtf(var + 1e-5f);
  ab2[f] = a;
  ab2[64 + f] = be[f] - mu * a;
}

__launch_bounds__(256)
__global__ void out_k(const float* __restrict__ atom,
                      const float* __restrict__ ab2,
                      float* __restrict__ out) {
  int gid = blockIdx.x * 256 + threadIdx.x;
  int stride = gridDim.x * 256;
  for (int i = gid; i < N_NODES * 16; i += stride) {
    float4 u = ((const float4*)out)[i];
    float4 x = ((const float4*)atom)[i];
    int f = (i & 15) * 4;
    float4 r;
    r.x = softplus_f(x.x + u.x * ab2[f + 0] + ab2[64 + f + 0]);
    r.y = softplus_f(x.y + u.y * ab2[f + 1] + ab2[64 + f + 1]);
    r.z = softplus_f(x.z + u.z * ab2[f + 2] + ab2[64 + f + 2]);
    r.w = softplus_f(x.w + u.w * ab2[f + 3] + ab2[64 + f + 3]);
    ((float4*)out)[i] = r;
  }
}

// ================= FALLBACK (round-1 two-pass path, known-good) ==============
template<int PASS>
__launch_bounds__(256, 2)
__global__ void edge_pass(const float* __restrict__ atom,
                          const float* __restrict__ nbr,
                          const int* __restrict__ esrc,
                          const int* __restrict__ edst,
                          const float* __restrict__ W,
                          const float* __restrict__ bvec,
                          float* __restrict__ stats,
                          const float* __restrict__ ab,
                          float* __restrict__ upd) {
  __shared__ short Wl[DOUT * LDW];
  __shared__ short Tl[EPB * LDW];
  __shared__ int eix[2 * EPB];

  const int tid = threadIdx.x;
  const int lane = tid & 63;
  const int wv = tid >> 6;
  const int l15 = lane & 15;
  const int lg = lane >> 4;

  for (int i = tid; i < DIN * DOUT; i += 256) {
    int k = i >> 7, n = i & 127;
    Wl[n * LDW + k] = f2bf(W[i]);
  }
  float bcol[8], acol[8], ccol[8];
  #pragma unroll
  for (int j = 0; j < 8; ++j) {
    int n = j * 16 + l15;
    bcol[j] = bvec[n];
    if constexpr (PASS == 1) { acol[j] = ab[n]; ccol[j] = ab[DOUT + n]; }
    else { acol[j] = 0.f; ccol[j] = 0.f; }
  }
  float fsum[8], fsq[8];
  #pragma unroll
  for (int j = 0; j < 8; ++j) { fsum[j] = 0.f; fsq[j] = 0.f; }

  for (int tile = blockIdx.x; tile < NTILES; tile += gridDim.x) {
    const int e0 = tile * EPB;
    __syncthreads();
    if (tid < EPB) eix[tid] = esrc[e0 + tid];
    else if (tid < 2 * EPB) eix[tid] = edst[e0 + tid - EPB];
    __syncthreads();
    for (int i = tid; i < EPB * 96; i += 256) {
      int row = i / 96;
      int cl = (i - row * 96) * 2;
      const float* p;
      if (cl < 64)       p = atom + (size_t)eix[row] * 64 + cl;
      else if (cl < 128) p = atom + (size_t)eix[EPB + row] * 64 + (cl - 64);
      else               p = nbr + (size_t)(e0 + row) * 64 + (cl - 128);
      float2 v = *(const float2*)p;
      unsigned pk = (unsigned)(unsigned short)f2bf(v.x)
                  | ((unsigned)(unsigned short)f2bf(v.y) << 16);
      *(unsigned*)&Tl[row * LDW + cl] = pk;
    }
    __syncthreads();
    f32x4 acc[8] = {};
    const int abase = (wv * 16 + l15) * LDW + lg * 8;
    #pragma unroll
    for (int kk = 0; kk < 6; ++kk) {
      bf16x8 afr = *(const bf16x8*)&Tl[abase + kk * 32];
      #pragma unroll
      for (int j = 0; j < 8; ++j) {
        bf16x8 bfr = *(const bf16x8*)&Wl[(j * 16 + l15) * LDW + lg * 8 + kk * 32];
        acc[j] = __builtin_amdgcn_mfma_f32_16x16x32_bf16(afr, bfr, acc[j], 0, 0, 0);
      }
    }
    if constexpr (PASS == 0) {
      #pragma unroll
      for (int j = 0; j < 8; ++j)
        #pragma unroll
        for (int r = 0; r < 4; ++r) {
          float z = acc[j][r] + bcol[j];
          fsum[j] += z; fsq[j] += z * z;
        }
    } else {
      #pragma unroll
      for (int r = 0; r < 4; ++r) {
        int row = wv * 16 + lg * 4 + r;
        int d = eix[EPB + row];
        float* urow = upd + (size_t)d * 64;
        #pragma unroll
        for (int j = 0; j < 4; ++j) {
          float f = (acc[j][r] + bcol[j]) * acol[j] + ccol[j];
          float g = (acc[j + 4][r] + bcol[j + 4]) * acol[j + 4] + ccol[j + 4];
          atomicAdd(&urow[j * 16 + l15], sigmoid_f(f) * softplus_f(g));
        }
      }
    }
  }
  if constexpr (PASS == 0) {
    #pragma unroll
    for (int j = 0; j < 8; ++j) {
      fsum[j] += __shfl_xor(fsum[j], 16, 64);
      fsum[j] += __shfl_xor(fsum[j], 32, 64);
      fsq[j]  += __shfl_xor(fsq[j], 16, 64);
      fsq[j]  += __shfl_xor(fsq[j], 32, 64);
    }
    __syncthreads();
    float* redf = (float*)Tl;
    if (lane < 16) {
      #pragma unroll
      for (int j = 0; j < 8; ++j) {
        redf[wv * 256 + j * 16 + lane] = fsum[j];
        redf[wv * 256 + 128 + j * 16 + lane] = fsq[j];
      }
    }
    __syncthreads();
    float s = redf[tid] + redf[256 + tid] + redf[512 + tid] + redf[768 + tid];
    atomicAdd(&stats[tid], s);
  }
}

// =============================================================================
extern "C" void kernel_launch(void* const* d_in, const int* in_sizes, int n_in,
                              void* d_out, int out_size, void* d_ws, size_t ws_size,
                              hipStream_t stream) {
  const float* atom = (const float*)d_in[0];
  const float* nbr  = (const float*)d_in[1];
  const int*   esrc = (const int*)d_in[2];
  const int*   edst = (const int*)d_in[3];
  const float* W    = (const float*)d_in[4];
  const float* bvec = (const float*)d_in[5];
  const float* g1   = (const float*)d_in[6];
  const float* b1   = (const float*)d_in[7];
  const float* g2   = (const float*)d_in[8];
  const float* b2   = (const float*)d_in[9];
  float* out = (float*)d_out;
  char* ws = (char*)d_ws;

  float* stats1 = (float*)ws;          // [256]
  float* ab1    = stats1 + 256;        // [256]
  float* stats2 = stats1 + 512;        // [128]
  float* ab2    = stats1 + 640;        // [128]

  const size_t OFF_ATOM = 4096;
  const size_t SZ_ATOM  = (size_t)N_NODES * ATOMF * 2;    //   6.4 MB
  const size_t OFF_NBR  = OFF_ATOM + SZ_ATOM;
  const size_t SZ_NBR   = (size_t)N_EDGES * ATOMF * 2;    // 102.4 MB
  const size_t OFF_ZT   = OFF_NBR + SZ_NBR;
  const size_t SZ_ZT    = (size_t)N_EDGES * DOUT * 2;     // 204.8 MB (z_csr)
  const size_t OFF_PERM = OFF_ZT + SZ_ZT;
  const size_t SZ_PERM  = (size_t)N_EDGES * 4;            //   3.2 MB
  const size_t OFF_DEG  = OFF_PERM + SZ_PERM;
  const size_t OFF_RP   = OFF_DEG + N_NODES * 4;
  const size_t OFF_CUR  = OFF_RP + (N_NODES + 1) * 4 + 12;   // keep 16B align
  const size_t NEED_NEW = OFF_CUR + N_NODES * 4;          // ~317.8 MB

  hipMemsetAsync(stats1, 0, 768 * sizeof(float), stream);

  if (ws_size >= NEED_NEW) {
    unsigned short* atom_bf = (unsigned short*)(ws + OFF_ATOM);
    unsigned short* nbr_bf  = (unsigned short*)(ws + OFF_NBR);
    unsigned short* zc      = (unsigned short*)(ws + OFF_ZT);
    int* iperm  = (int*)(ws + OFF_PERM);
    int* deg    = (int*)(ws + OFF_DEG);
    int* rowptr = (int*)(ws + OFF_RP);
    int* cursor = (int*)(ws + OFF_CUR);

    hipMemsetAsync(deg, 0, N_NODES * sizeof(int), stream);
    precvt_k<<<2048, 256, 0, stream>>>(atom, nbr, edst, atom_bf, nbr_bf, deg);
    scan_k<<<1, 1024, 0, stream>>>(deg, rowptr, cursor);
    fill_k<<<(N_EDGES + 255) / 256, 256, 0, stream>>>(edst, cursor, iperm);

    edge_gemm<<<1024, 256, 0, stream>>>(atom_bf, nbr_bf, esrc, edst, iperm,
                                        W, stats1, zc);
    finalize1_k<<<1, 128, 0, stream>>>(stats1, g1, b1, ab1);

    gather_k<<<(N_NODES + 3) / 4, 256, 0, stream>>>(zc, rowptr, ab1, out);
  } else {
    hipMemsetAsync(out, 0, (size_t)N_NODES * 64 * sizeof(float), stream);
    edge_pass<0><<<512, 256, 0, stream>>>(atom, nbr, esrc, edst, W, bvec,
                                          stats1, nullptr, nullptr);
    finalize1_k<<<1, 128, 0, stream>>>(stats1, g1, b1, ab1);
    edge_pass<1><<<512, 256, 0, stream>>>(atom, nbr, esrc, edst, W, bvec,
                                          nullptr, ab1, out);
  }

  stats2_k<<<512, 256, 0, stream>>>(out, stats2);
  finalize2_k<<<1, 64, 0, stream>>>(stats2, g2, b2, ab2);
  out_k<<<512, 256, 0, stream>>>(atom, ab2, out);
}